// Round 1
// baseline (188.378 us; speedup 1.0000x reference)
//
#include <hip/hip_runtime.h>
#include <math.h>

#define BATCH 256
#define DIN 784
#define DH 512
#define DOUT 10

__device__ __forceinline__ float softplus(float x) { return log1pf(expf(x)); }

// ---------------------------------------------------------------------------
// Kernel P: prep.
//  - blocks [0,400):  32x32 LDS-tiled transpose of softplus(w_sigma1) (512x784)
//                     -> Ws1T (784x512), + KL partials (sp - log sp)
//  - blocks [400,464): grid-stride sum of w_mu1^2 (784x512)
//  - block 464:       softplus(w_sigma2) -> Ws2 (10x512) + KL partials
//  - block 465:       sum w_mu2^2 + constant (-406528)
// All KL contributions: atomicAdd(kl, 0.5f * partial)
// ---------------------------------------------------------------------------
__global__ __launch_bounds__(256) void prep_kernel(
    const float* __restrict__ w_mu1, const float* __restrict__ w_sigma1,
    const float* __restrict__ w_mu2, const float* __restrict__ w_sigma2,
    float* __restrict__ Ws1T, float* __restrict__ Ws2,
    float* __restrict__ kl_out) {
  __shared__ float tile[32][33];
  __shared__ float rlds[4];
  const int bid = blockIdx.x;
  const int t = threadIdx.x;
  float acc = 0.0f;

  if (bid < 400) {
    const int th = (bid & 15) * 32;  // h tile base (16 tiles of 32 over 512)
    const int ti = (bid >> 4) * 32;  // i tile base (25 tiles of 32 over 784)
    const int tx = t & 31, ty = t >> 5;  // ty in 0..7
#pragma unroll
    for (int r = 0; r < 4; r++) {
      const int h = th + ty + r * 8;
      const int i = ti + tx;
      if (i < DIN) {
        const float s = softplus(w_sigma1[h * DIN + i]);
        tile[ty + r * 8][tx] = s;
        acc += s - logf(s);
      }
    }
    __syncthreads();
#pragma unroll
    for (int r = 0; r < 4; r++) {
      const int i = ti + ty + r * 8;
      const int h = th + tx;
      if (i < DIN) Ws1T[i * DH + h] = tile[tx][ty + r * 8];
    }
  } else if (bid < 464) {
    for (int idx = (bid - 400) * 256 + t; idx < DIN * DH; idx += 64 * 256) {
      const float w = w_mu1[idx];
      acc += w * w;
    }
  } else if (bid == 464) {
    for (int idx = t; idx < DOUT * DH; idx += 256) {
      const float s = softplus(w_sigma2[idx]);
      Ws2[idx] = s;
      acc += s - logf(s);
    }
  } else {
    for (int idx = t; idx < DH * DOUT; idx += 256) {
      const float w = w_mu2[idx];
      acc += w * w;
    }
    if (t == 0) acc += -(float)(DIN * DH + DH * DOUT);  // -406528
  }

  // block reduce (wave shuffle then LDS) -> one atomic per block
  for (int off = 32; off > 0; off >>= 1) acc += __shfl_down(acc, off);
  const int lane = t & 63, wv = t >> 6;
  if (lane == 0) rlds[wv] = acc;
  __syncthreads();
  if (t == 0) {
    atomicAdd(kl_out, 0.5f * (rlds[0] + rlds[1] + rlds[2] + rlds[3]));
  }
}

// ---------------------------------------------------------------------------
// Kernel 1: layer-1 dual GEMM. Tile: 16 b x 32 h per block, grid (16,16).
// Thread: h = h0 + (t&31), b in {b0 + t>>5, b0 + t>>5 + 8}.
// mu1[b,h] = dot(x[b,:], w_mu1[:,h]) ; q1[b,h] = dot(x[b,:]^2, Ws1T[:,h])
// Epilogue: m2 = relu(mu1 + b_mu1), d2 = (q1 + sp(b_sigma1)) * (mu1+b>0)
// ---------------------------------------------------------------------------
#define KC 112  // 784 = 7 * 112
__global__ __launch_bounds__(256) void layer1_kernel(
    const float* __restrict__ x, const float* __restrict__ w_mu1,
    const float* __restrict__ Ws1T, const float* __restrict__ b_mu1,
    const float* __restrict__ b_sigma1, float* __restrict__ m2,
    float* __restrict__ d2) {
  __shared__ float xs[16][KC];
  const int t = threadIdx.x;
  const int h0 = blockIdx.x * 32;
  const int b0 = blockIdx.y * 16;
  const int hl = t & 31, bl = t >> 5;  // bl in 0..7

  float mu_a = 0.f, mu_b = 0.f, q_a = 0.f, q_b = 0.f;

  for (int i0 = 0; i0 < DIN; i0 += KC) {
    __syncthreads();
    for (int f = t; f < 16 * KC; f += 256) {
      const int bb = f / KC, kk = f % KC;
      xs[bb][kk] = x[(b0 + bb) * DIN + i0 + kk];
    }
    __syncthreads();
    const float* wm = &w_mu1[(size_t)i0 * DH + h0 + hl];
    const float* wsp = &Ws1T[(size_t)i0 * DH + h0 + hl];
#pragma unroll 8
    for (int kk = 0; kk < KC; kk++) {
      const float wmv = wm[kk * DH];
      const float wsv = wsp[kk * DH];
      const float xa = xs[bl][kk];
      const float xb = xs[bl + 8][kk];
      mu_a = fmaf(wmv, xa, mu_a);
      mu_b = fmaf(wmv, xb, mu_b);
      q_a = fmaf(wsv, xa * xa, q_a);
      q_b = fmaf(wsv, xb * xb, q_b);
    }
  }

  const int h = h0 + hl;
  const float bm = b_mu1[h];
  const float sb = softplus(b_sigma1[h]);
  const float ma = mu_a + bm;
  const float mb = mu_b + bm;
  const int b_a = b0 + bl, b_b = b0 + bl + 8;
  m2[b_a * DH + h] = ma > 0.f ? ma : 0.f;
  m2[b_b * DH + h] = mb > 0.f ? mb : 0.f;
  d2[b_a * DH + h] = ma > 0.f ? (q_a + sb) : 0.f;
  d2[b_b * DH + h] = mb > 0.f ? (q_b + sb) : 0.f;
}

// ---------------------------------------------------------------------------
// Kernel 2: layer-2 + softmax + Jacobian sandwich. One block per batch row.
// 75 reduction values: mu3[10] (acc 0..9), quad2[10] (10..19), mid upper-tri
// [55] (20..74), reduced wave-shuffle then LDS.
// ---------------------------------------------------------------------------
__global__ __launch_bounds__(256) void layer2_kernel(
    const float* __restrict__ m2g, const float* __restrict__ d2g,
    const float* __restrict__ w_mu2, const float* __restrict__ Ws2,
    const float* __restrict__ b_mu2, const float* __restrict__ b_sigma2,
    float* __restrict__ out_p, float* __restrict__ out_sigma) {
  const int b = blockIdx.x, t = threadIdx.x;
  __shared__ float sm2[DH], sd2[DH];
  __shared__ float red[4][75];
  __shared__ float fin[75];
  __shared__ float mu3[10], pvec[10], trv[10], spb2[10];
  __shared__ float sig[10][10], Tm[10][10], cs[10], rs[10];

  sm2[t] = m2g[b * DH + t];
  sm2[t + 256] = m2g[b * DH + t + 256];
  sd2[t] = d2g[b * DH + t];
  sd2[t + 256] = d2g[b * DH + t + 256];
  __syncthreads();

  float acc[75];
#pragma unroll
  for (int i = 0; i < 75; i++) acc[i] = 0.f;

#pragma unroll
  for (int hh = 0; hh < 2; hh++) {
    const int h = t + hh * 256;
    const float m2h = sm2[h], d2h = sd2[h];
    const float msq = m2h * m2h;
    float wrow[10];
#pragma unroll
    for (int o = 0; o < 10; o++) wrow[o] = w_mu2[h * 10 + o];
#pragma unroll
    for (int o = 0; o < 10; o++) {
      acc[o] = fmaf(wrow[o], m2h, acc[o]);
      acc[10 + o] = fmaf(Ws2[o * DH + h], msq, acc[10 + o]);
    }
    int idx = 20;
#pragma unroll
    for (int o = 0; o < 10; o++) {
      const float wd = wrow[o] * d2h;
#pragma unroll
      for (int p = o; p < 10; p++) {
        acc[idx] = fmaf(wd, wrow[p], acc[idx]);
        idx++;
      }
    }
  }

  const int lane = t & 63, wv = t >> 6;
#pragma unroll
  for (int j = 0; j < 75; j++) {
    float v = acc[j];
    for (int off = 32; off > 0; off >>= 1) v += __shfl_down(v, off);
    if (lane == 0) red[wv][j] = v;
  }
  __syncthreads();
  if (t < 75) fin[t] = red[0][t] + red[1][t] + red[2][t] + red[3][t];
  __syncthreads();

  if (t < 10) {
    mu3[t] = fin[t] + b_mu2[t];
    spb2[t] = softplus(b_sigma2[t]);
    // faithful replication of the reshape-trace: tr[b,o] = tr_raw[o2, c]
    const int c0 = b * 10 + t;
    const int o2 = c0 >> 8, cc = c0 & 255;
    trv[t] = Ws2[o2 * DH + 2 * cc] * d2g[cc * DH + cc] +
             Ws2[o2 * DH + 2 * cc + 1] * d2g[cc * DH + 256 + cc];
  }
  __syncthreads();

  if (t == 0) {
    float mx = mu3[0];
#pragma unroll
    for (int o = 1; o < 10; o++) mx = fmaxf(mx, mu3[o]);
    float e[10], se = 0.f;
#pragma unroll
    for (int o = 0; o < 10; o++) {
      e[o] = expf(mu3[o] - mx);
      se += e[o];
    }
    const float inv = 1.f / se;
#pragma unroll
    for (int o = 0; o < 10; o++) pvec[o] = e[o] * inv;
  }
  __syncthreads();

  if (t < 100) {
    const int o = t / 10, p = t % 10;
    const int i0 = o < p ? o : p, j0 = o < p ? p : o;
    const int idx = 10 * i0 - (i0 * (i0 - 1)) / 2 + (j0 - i0);
    float v = fin[20 + idx];  // mid[o][p]
    if (o == p) v += trv[o] + fin[10 + o] + spb2[o];
    sig[o][p] = v;
  }
  __syncthreads();

  if (t < 10) {  // cs[k] = sum_j p[j] * sig[j][k]
    float s = 0.f;
#pragma unroll
    for (int j = 0; j < 10; j++) s = fmaf(pvec[j], sig[j][t], s);
    cs[t] = s;
  }
  __syncthreads();

  if (t < 100) {  // T[i][k] = p[i] * (sig[i][k] - cs[k])
    const int o = t / 10, p = t % 10;
    Tm[o][p] = pvec[o] * (sig[o][p] - cs[p]);
  }
  __syncthreads();

  if (t < 10) {  // rs[i] = sum_k T[i][k] * p[k]
    float s = 0.f;
#pragma unroll
    for (int k = 0; k < 10; k++) s = fmaf(Tm[t][k], pvec[k], s);
    rs[t] = s;
  }
  __syncthreads();

  if (t < 100) {  // Sigma_out[i][l] = p[l] * (T[i][l] - rs[i])
    const int o = t / 10, p = t % 10;
    out_sigma[b * 100 + t] = pvec[p] * (Tm[o][p] - rs[o]);
  }
  if (t < 10) out_p[b * 10 + t] = pvec[t];
}

extern "C" void kernel_launch(void* const* d_in, const int* in_sizes, int n_in,
                              void* d_out, int out_size, void* d_ws,
                              size_t ws_size, hipStream_t stream) {
  const float* x = (const float*)d_in[0];
  const float* w_mu1 = (const float*)d_in[1];
  const float* w_sigma1 = (const float*)d_in[2];
  const float* b_mu1 = (const float*)d_in[3];
  const float* b_sigma1 = (const float*)d_in[4];
  const float* w_mu2 = (const float*)d_in[5];
  const float* w_sigma2 = (const float*)d_in[6];
  const float* b_mu2 = (const float*)d_in[7];
  const float* b_sigma2 = (const float*)d_in[8];

  float* out = (float*)d_out;
  float* out_p = out;              // 256*10
  float* out_sigma = out + 2560;   // 256*100
  float* out_kl = out + 28160;     // 1

  char* ws = (char*)d_ws;
  float* Ws1T = (float*)ws;                                  // 784*512 floats
  float* Ws2 = (float*)(ws + (size_t)401408 * 4);            // 10*512
  float* m2 = (float*)(ws + (size_t)(401408 + 5120) * 4);    // 256*512
  float* d2 = (float*)(ws + (size_t)(401408 + 5120 + 131072) * 4);  // 256*512

  hipMemsetAsync(out_kl, 0, sizeof(float), stream);
  prep_kernel<<<466, 256, 0, stream>>>(w_mu1, w_sigma1, w_mu2, w_sigma2, Ws1T,
                                       Ws2, out_kl);
  layer1_kernel<<<dim3(16, 16), 256, 0, stream>>>(x, w_mu1, Ws1T, b_mu1,
                                                  b_sigma1, m2, d2);
  layer2_kernel<<<256, 256, 0, stream>>>(m2, d2, w_mu2, Ws2, b_mu2, b_sigma2,
                                         out_p, out_sigma);
}

// Round 2
// 142.561 us; speedup vs baseline: 1.3214x; 1.3214x over previous
//
#include <hip/hip_runtime.h>
#include <math.h>

#define BATCH 256
#define DIN 784
#define DH 512
#define DOUT 10
#define SPLITS 8
#define KSPL 98  // 784 / 8

__device__ __forceinline__ float softplus(float x) { return log1pf(expf(x)); }

// ---------------------------------------------------------------------------
// Kernel P: prep.
//  - blocks [0,400):  32x32 LDS-tiled transpose of softplus(w_sigma1) (512x784)
//                     -> Ws1T (784x512), + KL partials (sp - log sp)
//  - blocks [400,464): grid-stride sum of w_mu1^2 (784x512)
//  - block 464:       softplus(w_sigma2) -> Ws2 (10x512) + KL partials
//  - block 465:       sum w_mu2^2 + constant (-406528)
// ---------------------------------------------------------------------------
__global__ __launch_bounds__(256) void prep_kernel(
    const float* __restrict__ w_mu1, const float* __restrict__ w_sigma1,
    const float* __restrict__ w_mu2, const float* __restrict__ w_sigma2,
    float* __restrict__ Ws1T, float* __restrict__ Ws2,
    float* __restrict__ kl_out) {
  __shared__ float tile[32][33];
  __shared__ float rlds[4];
  const int bid = blockIdx.x;
  const int t = threadIdx.x;
  float acc = 0.0f;

  if (bid < 400) {
    const int th = (bid & 15) * 32;
    const int ti = (bid >> 4) * 32;
    const int tx = t & 31, ty = t >> 5;
#pragma unroll
    for (int r = 0; r < 4; r++) {
      const int h = th + ty + r * 8;
      const int i = ti + tx;
      if (i < DIN) {
        const float s = softplus(w_sigma1[h * DIN + i]);
        tile[ty + r * 8][tx] = s;
        acc += s - logf(s);
      }
    }
    __syncthreads();
#pragma unroll
    for (int r = 0; r < 4; r++) {
      const int i = ti + ty + r * 8;
      const int h = th + tx;
      if (i < DIN) Ws1T[i * DH + h] = tile[tx][ty + r * 8];
    }
  } else if (bid < 464) {
    for (int idx = (bid - 400) * 256 + t; idx < DIN * DH; idx += 64 * 256) {
      const float w = w_mu1[idx];
      acc += w * w;
    }
  } else if (bid == 464) {
    for (int idx = t; idx < DOUT * DH; idx += 256) {
      const float s = softplus(w_sigma2[idx]);
      Ws2[idx] = s;
      acc += s - logf(s);
    }
  } else {
    for (int idx = t; idx < DH * DOUT; idx += 256) {
      const float w = w_mu2[idx];
      acc += w * w;
    }
    if (t == 0) acc += -(float)(DIN * DH + DH * DOUT);  // -406528
  }

  for (int off = 32; off > 0; off >>= 1) acc += __shfl_down(acc, off);
  const int lane = t & 63, wv = t >> 6;
  if (lane == 0) rlds[wv] = acc;
  __syncthreads();
  if (t == 0) {
    atomicAdd(kl_out, 0.5f * (rlds[0] + rlds[1] + rlds[2] + rlds[3]));
  }
}

// ---------------------------------------------------------------------------
// Kernel 1: layer-1 dual GEMM, k-split. Grid (8 hTiles, 16 bTiles, 8 splits)
// = 1024 blocks (4/CU -> 16 waves/CU). Block tile: 64 h x 16 b, k-chunk 98.
// Thread: 2 h (float2 weight loads) x 2 b, 8 accumulators.
// Writes fp32 partials mu_part[s][b][h], q_part[s][b][h]; epilogue is fused
// into layer2.
// ---------------------------------------------------------------------------
__global__ __launch_bounds__(256) void gemm1_kernel(
    const float* __restrict__ x, const float* __restrict__ w_mu1,
    const float* __restrict__ Ws1T, float* __restrict__ mu_part,
    float* __restrict__ q_part) {
  __shared__ float xs[16][KSPL];
  const int t = threadIdx.x;
  const int h0 = blockIdx.x * 64;
  const int b0 = blockIdx.y * 16;
  const int s = blockIdx.z;
  const int i0 = s * KSPL;
  const int hl = (t & 31) * 2;  // even h offset within tile
  const int bl = t >> 5;        // 0..7

  float mu00 = 0.f, mu10 = 0.f, mu01 = 0.f, mu11 = 0.f;
  float q00 = 0.f, q10 = 0.f, q01 = 0.f, q11 = 0.f;

  for (int f = t; f < 16 * KSPL; f += 256) {
    const int bb = f / KSPL, kk = f - bb * KSPL;
    xs[bb][kk] = x[(b0 + bb) * DIN + i0 + kk];
  }
  __syncthreads();

  const float2* wm = (const float2*)&w_mu1[(size_t)i0 * DH + h0 + hl];
  const float2* wsp = (const float2*)&Ws1T[(size_t)i0 * DH + h0 + hl];
#pragma unroll 14
  for (int kk = 0; kk < KSPL; kk++) {
    const float2 wmv = wm[kk * (DH / 2)];
    const float2 wsv = wsp[kk * (DH / 2)];
    const float xa = xs[bl][kk];
    const float xb = xs[bl + 8][kk];
    const float xa2 = xa * xa;
    const float xb2 = xb * xb;
    mu00 = fmaf(wmv.x, xa, mu00);
    mu10 = fmaf(wmv.y, xa, mu10);
    mu01 = fmaf(wmv.x, xb, mu01);
    mu11 = fmaf(wmv.y, xb, mu11);
    q00 = fmaf(wsv.x, xa2, q00);
    q10 = fmaf(wsv.y, xa2, q10);
    q01 = fmaf(wsv.x, xb2, q01);
    q11 = fmaf(wsv.y, xb2, q11);
  }

  const int h = h0 + hl;
  const int bA = b0 + bl, bB = b0 + bl + 8;
  const size_t base = (size_t)s * (BATCH * DH);
  float2* mpA = (float2*)&mu_part[base + (size_t)bA * DH + h];
  float2* mpB = (float2*)&mu_part[base + (size_t)bB * DH + h];
  float2* qpA = (float2*)&q_part[base + (size_t)bA * DH + h];
  float2* qpB = (float2*)&q_part[base + (size_t)bB * DH + h];
  *mpA = make_float2(mu00, mu10);
  *mpB = make_float2(mu01, mu11);
  *qpA = make_float2(q00, q10);
  *qpB = make_float2(q01, q11);
}

// ---------------------------------------------------------------------------
// Kernel 2: fused layer-1 epilogue + layer-2 + softmax + Jacobian sandwich.
// One block (256 threads) per batch row. Reduces the 8 k-split partials,
// applies bias/softplus/ReLU/mask, then the 75-value (mu3/quad2/mid-tri)
// shuffle+LDS reduction over DH and the analytic softmax sandwich.
// ---------------------------------------------------------------------------
__global__ __launch_bounds__(256) void layer2_kernel(
    const float* __restrict__ mu_part, const float* __restrict__ q_part,
    const float* __restrict__ b_mu1, const float* __restrict__ b_sigma1,
    const float* __restrict__ w_mu2, const float* __restrict__ Ws2,
    const float* __restrict__ b_mu2, const float* __restrict__ b_sigma2,
    float* __restrict__ out_p, float* __restrict__ out_sigma) {
  const int b = blockIdx.x, t = threadIdx.x;
  __shared__ float red[4][75];
  __shared__ float fin[75];
  __shared__ float mu3[10], pvec[10], trv[10], spb2[10];
  __shared__ float sig[10][10], Tm[10][10], cs[10], rs[10];

  // reduce k-split partials for this batch's two h values per thread
  float musum0 = 0.f, musum1 = 0.f, qsum0 = 0.f, qsum1 = 0.f;
#pragma unroll
  for (int s2 = 0; s2 < SPLITS; s2++) {
    const size_t base = (size_t)s2 * (BATCH * DH) + (size_t)b * DH;
    musum0 += mu_part[base + t];
    musum1 += mu_part[base + t + 256];
    qsum0 += q_part[base + t];
    qsum1 += q_part[base + t + 256];
  }

  float m2v[2], d2v[2];
  {
    const float ma0 = musum0 + b_mu1[t];
    const float ma1 = musum1 + b_mu1[t + 256];
    m2v[0] = ma0 > 0.f ? ma0 : 0.f;
    m2v[1] = ma1 > 0.f ? ma1 : 0.f;
    d2v[0] = ma0 > 0.f ? (qsum0 + softplus(b_sigma1[t])) : 0.f;
    d2v[1] = ma1 > 0.f ? (qsum1 + softplus(b_sigma1[t + 256])) : 0.f;
  }

  float acc[75];
#pragma unroll
  for (int i = 0; i < 75; i++) acc[i] = 0.f;

#pragma unroll
  for (int hh = 0; hh < 2; hh++) {
    const int h = t + hh * 256;
    const float m2h = m2v[hh], d2h = d2v[hh];
    const float msq = m2h * m2h;
    float wrow[10];
#pragma unroll
    for (int o = 0; o < 10; o++) wrow[o] = w_mu2[h * 10 + o];
#pragma unroll
    for (int o = 0; o < 10; o++) {
      acc[o] = fmaf(wrow[o], m2h, acc[o]);
      acc[10 + o] = fmaf(Ws2[o * DH + h], msq, acc[10 + o]);
    }
    int idx = 20;
#pragma unroll
    for (int o = 0; o < 10; o++) {
      const float wd = wrow[o] * d2h;
#pragma unroll
      for (int p = o; p < 10; p++) {
        acc[idx] = fmaf(wd, wrow[p], acc[idx]);
        idx++;
      }
    }
  }

  const int lane = t & 63, wv = t >> 6;
#pragma unroll
  for (int j = 0; j < 75; j++) {
    float v = acc[j];
    for (int off = 32; off > 0; off >>= 1) v += __shfl_down(v, off);
    if (lane == 0) red[wv][j] = v;
  }
  __syncthreads();
  if (t < 75) fin[t] = red[0][t] + red[1][t] + red[2][t] + red[3][t];
  __syncthreads();

  if (t < 10) {
    mu3[t] = fin[t] + b_mu2[t];
    spb2[t] = softplus(b_sigma2[t]);
    // faithful replication of the reshape-trace: tr[b,o] = tr_raw[o2, c]
    // needs d2[cc][cc] and d2[cc][256+cc] for cc of OTHER batches ->
    // recompute from partials.
    const int c0 = b * 10 + t;
    const int o2 = c0 >> 8, cc = c0 & 255;
    float mua = b_mu1[cc], qa = 0.f;
    float mub = b_mu1[256 + cc], qb = 0.f;
#pragma unroll
    for (int s2 = 0; s2 < SPLITS; s2++) {
      const size_t base = (size_t)s2 * (BATCH * DH) + (size_t)cc * DH;
      mua += mu_part[base + cc];
      qa += q_part[base + cc];
      mub += mu_part[base + 256 + cc];
      qb += q_part[base + 256 + cc];
    }
    const float d2aa = mua > 0.f ? (qa + softplus(b_sigma1[cc])) : 0.f;
    const float d2bb = mub > 0.f ? (qb + softplus(b_sigma1[256 + cc])) : 0.f;
    trv[t] = Ws2[o2 * DH + 2 * cc] * d2aa + Ws2[o2 * DH + 2 * cc + 1] * d2bb;
  }
  __syncthreads();

  if (t == 0) {
    float mx = mu3[0];
#pragma unroll
    for (int o = 1; o < 10; o++) mx = fmaxf(mx, mu3[o]);
    float e[10], se = 0.f;
#pragma unroll
    for (int o = 0; o < 10; o++) {
      e[o] = expf(mu3[o] - mx);
      se += e[o];
    }
    const float inv = 1.f / se;
#pragma unroll
    for (int o = 0; o < 10; o++) pvec[o] = e[o] * inv;
  }
  __syncthreads();

  if (t < 100) {
    const int o = t / 10, p = t % 10;
    const int i0 = o < p ? o : p, j0 = o < p ? p : o;
    const int idx = 10 * i0 - (i0 * (i0 - 1)) / 2 + (j0 - i0);
    float v = fin[20 + idx];  // mid[o][p]
    if (o == p) v += trv[o] + fin[10 + o] + spb2[o];
    sig[o][p] = v;
  }
  __syncthreads();

  if (t < 10) {  // cs[k] = sum_j p[j] * sig[j][k]
    float s = 0.f;
#pragma unroll
    for (int j = 0; j < 10; j++) s = fmaf(pvec[j], sig[j][t], s);
    cs[t] = s;
  }
  __syncthreads();

  if (t < 100) {  // T[i][k] = p[i] * (sig[i][k] - cs[k])
    const int o = t / 10, p = t % 10;
    Tm[o][p] = pvec[o] * (sig[o][p] - cs[p]);
  }
  __syncthreads();

  if (t < 10) {  // rs[i] = sum_k T[i][k] * p[k]
    float s = 0.f;
#pragma unroll
    for (int k = 0; k < 10; k++) s = fmaf(Tm[t][k], pvec[k], s);
    rs[t] = s;
  }
  __syncthreads();

  if (t < 100) {  // Sigma_out[i][l] = p[l] * (T[i][l] - rs[i])
    const int o = t / 10, p = t % 10;
    out_sigma[b * 100 + t] = pvec[p] * (Tm[o][p] - rs[o]);
  }
  if (t < 10) out_p[b * 10 + t] = pvec[t];
}

extern "C" void kernel_launch(void* const* d_in, const int* in_sizes, int n_in,
                              void* d_out, int out_size, void* d_ws,
                              size_t ws_size, hipStream_t stream) {
  const float* x = (const float*)d_in[0];
  const float* w_mu1 = (const float*)d_in[1];
  const float* w_sigma1 = (const float*)d_in[2];
  const float* b_mu1 = (const float*)d_in[3];
  const float* b_sigma1 = (const float*)d_in[4];
  const float* w_mu2 = (const float*)d_in[5];
  const float* w_sigma2 = (const float*)d_in[6];
  const float* b_mu2 = (const float*)d_in[7];
  const float* b_sigma2 = (const float*)d_in[8];

  float* out = (float*)d_out;
  float* out_p = out;             // 256*10
  float* out_sigma = out + 2560;  // 256*100
  float* out_kl = out + 28160;    // 1

  char* ws = (char*)d_ws;
  float* Ws1T = (float*)ws;                        // 784*512
  float* Ws2 = (float*)(ws + (size_t)401408 * 4);  // 10*512
  float* mu_part = (float*)(ws + (size_t)(401408 + 5120) * 4);  // 8*256*512
  float* q_part =
      (float*)(ws + (size_t)(401408 + 5120 + SPLITS * BATCH * DH) * 4);

  hipMemsetAsync(out_kl, 0, sizeof(float), stream);
  prep_kernel<<<466, 256, 0, stream>>>(w_mu1, w_sigma1, w_mu2, w_sigma2, Ws1T,
                                       Ws2, out_kl);
  gemm1_kernel<<<dim3(8, 16, 8), 256, 0, stream>>>(x, w_mu1, Ws1T, mu_part,
                                                   q_part);
  layer2_kernel<<<256, 256, 0, stream>>>(mu_part, q_part, b_mu1, b_sigma1,
                                         w_mu2, Ws2, b_mu2, b_sigma2, out_p,
                                         out_sigma);
}

// Round 3
// 141.659 us; speedup vs baseline: 1.3298x; 1.0064x over previous
//
#include <hip/hip_runtime.h>
#include <math.h>

#define BATCH 256
#define DIN 784
#define DH 512
#define DOUT 10
#define SPLITS 8
#define KSPL 98  // 784 / 8

__device__ __forceinline__ float softplus(float x) { return log1pf(expf(x)); }

// ---------------------------------------------------------------------------
// Kernel 1: layer-1 dual GEMM, k-split, with fused softplus(w_sigma1) staging
// and fused KL partial reductions. Grid (8 hTiles, 16 bTiles, 8 splits) =
// 1024 blocks. Block tile: 64 h x 16 b, k-chunk 98. Thread: 2 h x 2 b.
//   mu_part[s][b][h] = sum_k x[b,k] * w_mu1[k,h]
//   q_part [s][b][h] = sum_k x[b,k]^2 * softplus(w_sigma1[h,k])
// KL partials (no atomics, no init): 136 slots in kl_part
//   y==0 blocks: sum (sp - log sp) over their softplus tile  -> slot x*8+z
//   y==1 blocks: sum w_mu1^2 over their (k,h) range          -> slot 64+x*8+z
//   y==2,x==0:   sum sp(ws2)-log sp(ws2) + w_mu2^2 slice     -> slot 128+z
// ---------------------------------------------------------------------------
__global__ __launch_bounds__(256) void gemm1_kernel(
    const float* __restrict__ x, const float* __restrict__ w_mu1,
    const float* __restrict__ w_sigma1, const float* __restrict__ w_mu2,
    const float* __restrict__ w_sigma2, float* __restrict__ mu_part,
    float* __restrict__ q_part, float* __restrict__ kl_part) {
  __shared__ float xs[16][KSPL];
  __shared__ float wst[KSPL][66];  // [k][h], pad 64->66 (2-way max, free)
  __shared__ float rlds[4];
  const int t = threadIdx.x;
  const int h0 = blockIdx.x * 64;
  const int b0 = blockIdx.y * 16;
  const int s = blockIdx.z;
  const int i0 = s * KSPL;
  const int hl = (t & 31) * 2;  // even h offset in tile
  const int bl = t >> 5;        // 0..7

  // stage x rows
  for (int f = t; f < 16 * KSPL; f += 256) {
    const int bb = f / KSPL, kk = f - bb * KSPL;
    xs[bb][kk] = x[(b0 + bb) * DIN + i0 + kk];
  }
  // stage softplus(w_sigma1) tile, transposed to [k][h]
  for (int f = t; f < 64 * KSPL; f += 256) {
    const int hh = f / KSPL, kk = f - hh * KSPL;
    wst[kk][hh] = softplus(w_sigma1[(h0 + hh) * DIN + i0 + kk]);
  }
  __syncthreads();

  float mu00 = 0.f, mu10 = 0.f, mu01 = 0.f, mu11 = 0.f;
  float q00 = 0.f, q10 = 0.f, q01 = 0.f, q11 = 0.f;

  const float2* wm = (const float2*)&w_mu1[(size_t)i0 * DH + h0 + hl];
#pragma unroll 14
  for (int kk = 0; kk < KSPL; kk++) {
    const float2 wmv = wm[kk * (DH / 2)];
    const float2 wsv = *(const float2*)&wst[kk][hl];
    const float xa = xs[bl][kk];
    const float xb = xs[bl + 8][kk];
    const float xa2 = xa * xa;
    const float xb2 = xb * xb;
    mu00 = fmaf(wmv.x, xa, mu00);
    mu10 = fmaf(wmv.y, xa, mu10);
    mu01 = fmaf(wmv.x, xb, mu01);
    mu11 = fmaf(wmv.y, xb, mu11);
    q00 = fmaf(wsv.x, xa2, q00);
    q10 = fmaf(wsv.y, xa2, q10);
    q01 = fmaf(wsv.x, xb2, q01);
    q11 = fmaf(wsv.y, xb2, q11);
  }

  const int h = h0 + hl;
  const int bA = b0 + bl, bB = b0 + bl + 8;
  const size_t base = (size_t)s * (BATCH * DH);
  *(float2*)&mu_part[base + (size_t)bA * DH + h] = make_float2(mu00, mu10);
  *(float2*)&mu_part[base + (size_t)bB * DH + h] = make_float2(mu01, mu11);
  *(float2*)&q_part[base + (size_t)bA * DH + h] = make_float2(q00, q10);
  *(float2*)&q_part[base + (size_t)bB * DH + h] = make_float2(q01, q11);

  // ---- fused KL partials ----
  float kl = 0.f;
  int slot = -1;
  if (blockIdx.y == 0) {
    for (int f = t; f < 64 * KSPL; f += 256) {
      const int hh = f / KSPL, kk = f - hh * KSPL;
      const float sv = wst[kk][hh];
      kl += sv - logf(sv);
    }
    slot = blockIdx.x * 8 + s;
  } else if (blockIdx.y == 1) {
#pragma unroll 14
    for (int kk = 0; kk < KSPL; kk++) {
      const float2 wmv = wm[kk * (DH / 2)];
      kl = fmaf(wmv.x, wmv.x, kl);
      kl = fmaf(wmv.y, wmv.y, kl);
    }
    slot = 64 + blockIdx.x * 8 + s;
  } else if (blockIdx.y == 2 && blockIdx.x == 0) {
    for (int idx = s * 640 + t; idx < s * 640 + 640; idx += 256) {
      const float sv = softplus(w_sigma2[idx]);
      const float wv = w_mu2[idx];
      kl += sv - logf(sv);
      kl = fmaf(wv, wv, kl);
    }
    slot = 128 + s;
  }

  for (int off = 32; off > 0; off >>= 1) kl += __shfl_down(kl, off);
  const int lane = t & 63, wv = t >> 6;
  if (lane == 0) rlds[wv] = kl;
  __syncthreads();
  if (t == 0 && slot >= 0)
    kl_part[slot] = rlds[0] + rlds[1] + rlds[2] + rlds[3];
}

// ---------------------------------------------------------------------------
// Kernel 2: fused layer-1 epilogue + layer-2 + softmax + Jacobian sandwich +
// KL finalize. One block (256 threads) per batch row.
// ---------------------------------------------------------------------------
__global__ __launch_bounds__(256) void layer2_kernel(
    const float* __restrict__ mu_part, const float* __restrict__ q_part,
    const float* __restrict__ b_mu1, const float* __restrict__ b_sigma1,
    const float* __restrict__ w_mu2, const float* __restrict__ w_sigma2,
    const float* __restrict__ b_mu2, const float* __restrict__ b_sigma2,
    const float* __restrict__ kl_part, float* __restrict__ out_p,
    float* __restrict__ out_sigma, float* __restrict__ out_kl) {
  const int b = blockIdx.x, t = threadIdx.x;
  __shared__ float red[4][75];
  __shared__ float fin[75];
  __shared__ float mu3[10], pvec[10], trv[10], spb2[10];
  __shared__ float sig[10][10], Tm[10][10], cs[10], rs[10];
  __shared__ float klred[4];

  // reduce k-split partials for this batch's two h values per thread
  float musum0 = 0.f, musum1 = 0.f, qsum0 = 0.f, qsum1 = 0.f;
#pragma unroll
  for (int s2 = 0; s2 < SPLITS; s2++) {
    const size_t base = (size_t)s2 * (BATCH * DH) + (size_t)b * DH;
    musum0 += mu_part[base + t];
    musum1 += mu_part[base + t + 256];
    qsum0 += q_part[base + t];
    qsum1 += q_part[base + t + 256];
  }

  float m2v[2], d2v[2];
  {
    const float ma0 = musum0 + b_mu1[t];
    const float ma1 = musum1 + b_mu1[t + 256];
    m2v[0] = ma0 > 0.f ? ma0 : 0.f;
    m2v[1] = ma1 > 0.f ? ma1 : 0.f;
    d2v[0] = ma0 > 0.f ? (qsum0 + softplus(b_sigma1[t])) : 0.f;
    d2v[1] = ma1 > 0.f ? (qsum1 + softplus(b_sigma1[t + 256])) : 0.f;
  }

  float acc[75];
#pragma unroll
  for (int i = 0; i < 75; i++) acc[i] = 0.f;

#pragma unroll
  for (int hh = 0; hh < 2; hh++) {
    const int h = t + hh * 256;
    const float m2h = m2v[hh], d2h = d2v[hh];
    const float msq = m2h * m2h;
    float wrow[10];
#pragma unroll
    for (int o = 0; o < 10; o++) wrow[o] = w_mu2[h * 10 + o];
#pragma unroll
    for (int o = 0; o < 10; o++) {
      acc[o] = fmaf(wrow[o], m2h, acc[o]);
      acc[10 + o] = fmaf(softplus(w_sigma2[o * DH + h]), msq, acc[10 + o]);
    }
    int idx = 20;
#pragma unroll
    for (int o = 0; o < 10; o++) {
      const float wd = wrow[o] * d2h;
#pragma unroll
      for (int p = o; p < 10; p++) {
        acc[idx] = fmaf(wd, wrow[p], acc[idx]);
        idx++;
      }
    }
  }

  const int lane = t & 63, wv = t >> 6;
#pragma unroll
  for (int j = 0; j < 75; j++) {
    float v = acc[j];
    for (int off = 32; off > 0; off >>= 1) v += __shfl_down(v, off);
    if (lane == 0) red[wv][j] = v;
  }
  __syncthreads();
  if (t < 75) fin[t] = red[0][t] + red[1][t] + red[2][t] + red[3][t];
  __syncthreads();

  if (t < 10) {
    mu3[t] = fin[t] + b_mu2[t];
    spb2[t] = softplus(b_sigma2[t]);
    // faithful replication of the reshape-trace: tr[b,o] = tr_raw[o2, c];
    // needs d2[cc][cc], d2[cc][256+cc] of OTHER batches -> recompute.
    const int c0 = b * 10 + t;
    const int o2 = c0 >> 8, cc = c0 & 255;
    float mua = b_mu1[cc], qa = 0.f;
    float mub = b_mu1[256 + cc], qb = 0.f;
#pragma unroll
    for (int s2 = 0; s2 < SPLITS; s2++) {
      const size_t base = (size_t)s2 * (BATCH * DH) + (size_t)cc * DH;
      mua += mu_part[base + cc];
      qa += q_part[base + cc];
      mub += mu_part[base + 256 + cc];
      qb += q_part[base + 256 + cc];
    }
    const float d2aa = mua > 0.f ? (qa + softplus(b_sigma1[cc])) : 0.f;
    const float d2bb = mub > 0.f ? (qb + softplus(b_sigma1[256 + cc])) : 0.f;
    trv[t] = softplus(w_sigma2[o2 * DH + 2 * cc]) * d2aa +
             softplus(w_sigma2[o2 * DH + 2 * cc + 1]) * d2bb;
  }
  __syncthreads();

  if (t == 0) {
    float mx = mu3[0];
#pragma unroll
    for (int o = 1; o < 10; o++) mx = fmaxf(mx, mu3[o]);
    float e[10], se = 0.f;
#pragma unroll
    for (int o = 0; o < 10; o++) {
      e[o] = expf(mu3[o] - mx);
      se += e[o];
    }
    const float inv = 1.f / se;
#pragma unroll
    for (int o = 0; o < 10; o++) pvec[o] = e[o] * inv;
  }
  __syncthreads();

  if (t < 100) {
    const int o = t / 10, p = t % 10;
    const int i0 = o < p ? o : p, j0 = o < p ? p : o;
    const int idx = 10 * i0 - (i0 * (i0 - 1)) / 2 + (j0 - i0);
    float v = fin[20 + idx];  // mid[o][p]
    if (o == p) v += trv[o] + fin[10 + o] + spb2[o];
    sig[o][p] = v;
  }
  __syncthreads();

  if (t < 10) {  // cs[k] = sum_j p[j] * sig[j][k]
    float s = 0.f;
#pragma unroll
    for (int j = 0; j < 10; j++) s = fmaf(pvec[j], sig[j][t], s);
    cs[t] = s;
  }
  __syncthreads();

  if (t < 100) {  // T[i][k] = p[i] * (sig[i][k] - cs[k])
    const int o = t / 10, p = t % 10;
    Tm[o][p] = pvec[o] * (sig[o][p] - cs[p]);
  }
  __syncthreads();

  if (t < 10) {  // rs[i] = sum_k T[i][k] * p[k]
    float s = 0.f;
#pragma unroll
    for (int k = 0; k < 10; k++) s = fmaf(Tm[t][k], pvec[k], s);
    rs[t] = s;
  }
  __syncthreads();

  if (t < 100) {  // Sigma_out[i][l] = p[l] * (T[i][l] - rs[i])
    const int o = t / 10, p = t % 10;
    out_sigma[b * 100 + t] = pvec[p] * (Tm[o][p] - rs[o]);
  }
  if (t < 10) out_p[b * 10 + t] = pvec[t];

  // ---- KL finalize (block 0 only; sync executed uniformly by all) ----
  float klv = (b == 0 && t < 136) ? kl_part[t] : 0.f;
  for (int off = 32; off > 0; off >>= 1) klv += __shfl_down(klv, off);
  if (lane == 0) klred[wv] = klv;
  __syncthreads();
  if (b == 0 && t == 0) {
    out_kl[0] =
        0.5f * (klred[0] + klred[1] + klred[2] + klred[3] - 406528.0f);
  }
}

extern "C" void kernel_launch(void* const* d_in, const int* in_sizes, int n_in,
                              void* d_out, int out_size, void* d_ws,
                              size_t ws_size, hipStream_t stream) {
  const float* x = (const float*)d_in[0];
  const float* w_mu1 = (const float*)d_in[1];
  const float* w_sigma1 = (const float*)d_in[2];
  const float* b_mu1 = (const float*)d_in[3];
  const float* b_sigma1 = (const float*)d_in[4];
  const float* w_mu2 = (const float*)d_in[5];
  const float* w_sigma2 = (const float*)d_in[6];
  const float* b_mu2 = (const float*)d_in[7];
  const float* b_sigma2 = (const float*)d_in[8];

  float* out = (float*)d_out;
  float* out_p = out;             // 256*10
  float* out_sigma = out + 2560;  // 256*100
  float* out_kl = out + 28160;    // 1

  float* ws = (float*)d_ws;
  float* mu_part = ws;                            // 8*256*512
  float* q_part = ws + SPLITS * BATCH * DH;       // 8*256*512
  float* kl_part = ws + 2 * SPLITS * BATCH * DH;  // 136

  gemm1_kernel<<<dim3(8, 16, 8), 256, 0, stream>>>(
      x, w_mu1, w_sigma1, w_mu2, w_sigma2, mu_part, q_part, kl_part);
  layer2_kernel<<<256, 256, 0, stream>>>(mu_part, q_part, b_mu1, b_sigma1,
                                         w_mu2, w_sigma2, b_mu2, b_sigma2,
                                         kl_part, out_p, out_sigma, out_kl);
}

// Round 4
// 130.207 us; speedup vs baseline: 1.4468x; 1.0880x over previous
//
#include <hip/hip_runtime.h>
#include <math.h>

#define BATCH 256
#define DIN 784
#define DH 512
#define DOUT 10
#define SPLITS 8
#define KSPL 98  // 784 / 8

// Fast softplus: inputs w_sigma* are uniform[-12,-2] by construction, so
// exp(x) in [6e-6, 0.135]; native v_exp_f32/v_log_f32 give ~1e-7 rel error,
// ~1e-4 absolute on the summed outputs -- threshold is ~2.5e4.
__device__ __forceinline__ float softplus(float x) {
  return __logf(1.0f + __expf(x));
}

// ---------------------------------------------------------------------------
// Kernel 1: layer-1 dual GEMM, k-split, with fused softplus(w_sigma1) staging
// and fused KL partial reductions. Grid (8 hTiles, 16 bTiles, 8 splits) =
// 1024 blocks. Block tile: 64 h x 16 b, k-chunk 98. Thread: 2 h x 2 b.
//   mu_part[s][b][h] = sum_k x[b,k] * w_mu1[k,h]
//   q_part [s][b][h] = sum_k x[b,k]^2 * softplus(w_sigma1[h,k])
// KL partials (no atomics, no init): 136 slots in kl_part
//   y==0 blocks: sum (sp - log sp) over their softplus tile  -> slot x*8+z
//   y==1 blocks: sum w_mu1^2 over their (k,h) range          -> slot 64+x*8+z
//   y==2,x==0:   sum sp(ws2)-log sp(ws2) + w_mu2^2 slice     -> slot 128+z
// ---------------------------------------------------------------------------
__global__ __launch_bounds__(256) void gemm1_kernel(
    const float* __restrict__ x, const float* __restrict__ w_mu1,
    const float* __restrict__ w_sigma1, const float* __restrict__ w_mu2,
    const float* __restrict__ w_sigma2, float* __restrict__ mu_part,
    float* __restrict__ q_part, float* __restrict__ kl_part) {
  __shared__ float xs[16][KSPL];
  __shared__ float wst[KSPL][66];  // [k][h], pad 64->66 (2-way max, free)
  __shared__ float rlds[4];
  const int t = threadIdx.x;
  const int h0 = blockIdx.x * 64;
  const int b0 = blockIdx.y * 16;
  const int s = blockIdx.z;
  const int i0 = s * KSPL;
  const int hl = (t & 31) * 2;  // even h offset in tile
  const int bl = t >> 5;        // 0..7

  // stage x rows
  for (int f = t; f < 16 * KSPL; f += 256) {
    const int bb = f / KSPL, kk = f - bb * KSPL;
    xs[bb][kk] = x[(b0 + bb) * DIN + i0 + kk];
  }
  // stage softplus(w_sigma1) tile, transposed to [k][h]
  for (int f = t; f < 64 * KSPL; f += 256) {
    const int hh = f / KSPL, kk = f - hh * KSPL;
    wst[kk][hh] = softplus(w_sigma1[(h0 + hh) * DIN + i0 + kk]);
  }
  __syncthreads();

  float mu00 = 0.f, mu10 = 0.f, mu01 = 0.f, mu11 = 0.f;
  float q00 = 0.f, q10 = 0.f, q01 = 0.f, q11 = 0.f;

  const float2* wm = (const float2*)&w_mu1[(size_t)i0 * DH + h0 + hl];
#pragma unroll 14
  for (int kk = 0; kk < KSPL; kk++) {
    const float2 wmv = wm[kk * (DH / 2)];
    const float2 wsv = *(const float2*)&wst[kk][hl];
    const float xa = xs[bl][kk];
    const float xb = xs[bl + 8][kk];
    const float xa2 = xa * xa;
    const float xb2 = xb * xb;
    mu00 = fmaf(wmv.x, xa, mu00);
    mu10 = fmaf(wmv.y, xa, mu10);
    mu01 = fmaf(wmv.x, xb, mu01);
    mu11 = fmaf(wmv.y, xb, mu11);
    q00 = fmaf(wsv.x, xa2, q00);
    q10 = fmaf(wsv.y, xa2, q10);
    q01 = fmaf(wsv.x, xb2, q01);
    q11 = fmaf(wsv.y, xb2, q11);
  }

  const int h = h0 + hl;
  const int bA = b0 + bl, bB = b0 + bl + 8;
  const size_t base = (size_t)s * (BATCH * DH);
  *(float2*)&mu_part[base + (size_t)bA * DH + h] = make_float2(mu00, mu10);
  *(float2*)&mu_part[base + (size_t)bB * DH + h] = make_float2(mu01, mu11);
  *(float2*)&q_part[base + (size_t)bA * DH + h] = make_float2(q00, q10);
  *(float2*)&q_part[base + (size_t)bB * DH + h] = make_float2(q01, q11);

  // ---- fused KL partials ----
  float kl = 0.f;
  int slot = -1;
  if (blockIdx.y == 0) {
    for (int f = t; f < 64 * KSPL; f += 256) {
      const int hh = f / KSPL, kk = f - hh * KSPL;
      const float sv = wst[kk][hh];
      kl += sv - __logf(sv);
    }
    slot = blockIdx.x * 8 + s;
  } else if (blockIdx.y == 1) {
#pragma unroll 14
    for (int kk = 0; kk < KSPL; kk++) {
      const float2 wmv = wm[kk * (DH / 2)];
      kl = fmaf(wmv.x, wmv.x, kl);
      kl = fmaf(wmv.y, wmv.y, kl);
    }
    slot = 64 + blockIdx.x * 8 + s;
  } else if (blockIdx.y == 2 && blockIdx.x == 0) {
    for (int idx = s * 640 + t; idx < s * 640 + 640; idx += 256) {
      const float sv = softplus(w_sigma2[idx]);
      const float wv = w_mu2[idx];
      kl += sv - __logf(sv);
      kl = fmaf(wv, wv, kl);
    }
    slot = 128 + s;
  }

  for (int off = 32; off > 0; off >>= 1) kl += __shfl_down(kl, off);
  const int lane = t & 63, wv = t >> 6;
  if (lane == 0) rlds[wv] = kl;
  __syncthreads();
  if (t == 0 && slot >= 0)
    kl_part[slot] = rlds[0] + rlds[1] + rlds[2] + rlds[3];
}

// ---------------------------------------------------------------------------
// Kernel 2: fused layer-1 epilogue + layer-2 + softmax + Jacobian sandwich +
// KL finalize. One block (256 threads) per batch row.
// ---------------------------------------------------------------------------
__global__ __launch_bounds__(256) void layer2_kernel(
    const float* __restrict__ mu_part, const float* __restrict__ q_part,
    const float* __restrict__ b_mu1, const float* __restrict__ b_sigma1,
    const float* __restrict__ w_mu2, const float* __restrict__ w_sigma2,
    const float* __restrict__ b_mu2, const float* __restrict__ b_sigma2,
    const float* __restrict__ kl_part, float* __restrict__ out_p,
    float* __restrict__ out_sigma, float* __restrict__ out_kl) {
  const int b = blockIdx.x, t = threadIdx.x;
  __shared__ float red[4][75];
  __shared__ float fin[75];
  __shared__ float mu3[10], pvec[10], trv[10], spb2[10];
  __shared__ float sig[10][10], Tm[10][10], cs[10], rs[10];
  __shared__ float klred[4];

  // reduce k-split partials for this batch's two h values per thread
  float musum0 = 0.f, musum1 = 0.f, qsum0 = 0.f, qsum1 = 0.f;
#pragma unroll
  for (int s2 = 0; s2 < SPLITS; s2++) {
    const size_t base = (size_t)s2 * (BATCH * DH) + (size_t)b * DH;
    musum0 += mu_part[base + t];
    musum1 += mu_part[base + t + 256];
    qsum0 += q_part[base + t];
    qsum1 += q_part[base + t + 256];
  }

  float m2v[2], d2v[2];
  {
    const float ma0 = musum0 + b_mu1[t];
    const float ma1 = musum1 + b_mu1[t + 256];
    m2v[0] = ma0 > 0.f ? ma0 : 0.f;
    m2v[1] = ma1 > 0.f ? ma1 : 0.f;
    d2v[0] = ma0 > 0.f ? (qsum0 + softplus(b_sigma1[t])) : 0.f;
    d2v[1] = ma1 > 0.f ? (qsum1 + softplus(b_sigma1[t + 256])) : 0.f;
  }

  float acc[75];
#pragma unroll
  for (int i = 0; i < 75; i++) acc[i] = 0.f;

#pragma unroll
  for (int hh = 0; hh < 2; hh++) {
    const int h = t + hh * 256;
    const float m2h = m2v[hh], d2h = d2v[hh];
    const float msq = m2h * m2h;
    float wrow[10];
#pragma unroll
    for (int o = 0; o < 10; o++) wrow[o] = w_mu2[h * 10 + o];
#pragma unroll
    for (int o = 0; o < 10; o++) {
      acc[o] = fmaf(wrow[o], m2h, acc[o]);
      acc[10 + o] = fmaf(softplus(w_sigma2[o * DH + h]), msq, acc[10 + o]);
    }
    int idx = 20;
#pragma unroll
    for (int o = 0; o < 10; o++) {
      const float wd = wrow[o] * d2h;
#pragma unroll
      for (int p = o; p < 10; p++) {
        acc[idx] = fmaf(wd, wrow[p], acc[idx]);
        idx++;
      }
    }
  }

  const int lane = t & 63, wv = t >> 6;
#pragma unroll
  for (int j = 0; j < 75; j++) {
    float v = acc[j];
    for (int off = 32; off > 0; off >>= 1) v += __shfl_down(v, off);
    if (lane == 0) red[wv][j] = v;
  }
  __syncthreads();
  if (t < 75) fin[t] = red[0][t] + red[1][t] + red[2][t] + red[3][t];
  __syncthreads();

  if (t < 10) {
    mu3[t] = fin[t] + b_mu2[t];
    spb2[t] = softplus(b_sigma2[t]);
    // faithful replication of the reshape-trace: tr[b,o] = tr_raw[o2, c];
    // needs d2[cc][cc], d2[cc][256+cc] of OTHER batches -> recompute.
    const int c0 = b * 10 + t;
    const int o2 = c0 >> 8, cc = c0 & 255;
    float mua = b_mu1[cc], qa = 0.f;
    float mub = b_mu1[256 + cc], qb = 0.f;
#pragma unroll
    for (int s2 = 0; s2 < SPLITS; s2++) {
      const size_t base = (size_t)s2 * (BATCH * DH) + (size_t)cc * DH;
      mua += mu_part[base + cc];
      qa += q_part[base + cc];
      mub += mu_part[base + 256 + cc];
      qb += q_part[base + 256 + cc];
    }
    const float d2aa = mua > 0.f ? (qa + softplus(b_sigma1[cc])) : 0.f;
    const float d2bb = mub > 0.f ? (qb + softplus(b_sigma1[256 + cc])) : 0.f;
    trv[t] = softplus(w_sigma2[o2 * DH + 2 * cc]) * d2aa +
             softplus(w_sigma2[o2 * DH + 2 * cc + 1]) * d2bb;
  }
  __syncthreads();

  if (t == 0) {
    float mx = mu3[0];
#pragma unroll
    for (int o = 1; o < 10; o++) mx = fmaxf(mx, mu3[o]);
    float e[10], se = 0.f;
#pragma unroll
    for (int o = 0; o < 10; o++) {
      e[o] = expf(mu3[o] - mx);
      se += e[o];
    }
    const float inv = 1.f / se;
#pragma unroll
    for (int o = 0; o < 10; o++) pvec[o] = e[o] * inv;
  }
  __syncthreads();

  if (t < 100) {
    const int o = t / 10, p = t % 10;
    const int i0 = o < p ? o : p, j0 = o < p ? p : o;
    const int idx = 10 * i0 - (i0 * (i0 - 1)) / 2 + (j0 - i0);
    float v = fin[20 + idx];  // mid[o][p]
    if (o == p) v += trv[o] + fin[10 + o] + spb2[o];
    sig[o][p] = v;
  }
  __syncthreads();

  if (t < 10) {  // cs[k] = sum_j p[j] * sig[j][k]
    float s = 0.f;
#pragma unroll
    for (int j = 0; j < 10; j++) s = fmaf(pvec[j], sig[j][t], s);
    cs[t] = s;
  }
  __syncthreads();

  if (t < 100) {  // T[i][k] = p[i] * (sig[i][k] - cs[k])
    const int o = t / 10, p = t % 10;
    Tm[o][p] = pvec[o] * (sig[o][p] - cs[p]);
  }
  __syncthreads();

  if (t < 10) {  // rs[i] = sum_k T[i][k] * p[k]
    float s = 0.f;
#pragma unroll
    for (int k = 0; k < 10; k++) s = fmaf(Tm[t][k], pvec[k], s);
    rs[t] = s;
  }
  __syncthreads();

  if (t < 100) {  // Sigma_out[i][l] = p[l] * (T[i][l] - rs[i])
    const int o = t / 10, p = t % 10;
    out_sigma[b * 100 + t] = pvec[p] * (Tm[o][p] - rs[o]);
  }
  if (t < 10) out_p[b * 10 + t] = pvec[t];

  // ---- KL finalize (block 0 only; sync executed uniformly by all) ----
  float klv = (b == 0 && t < 136) ? kl_part[t] : 0.f;
  for (int off = 32; off > 0; off >>= 1) klv += __shfl_down(klv, off);
  if (lane == 0) klred[wv] = klv;
  __syncthreads();
  if (b == 0 && t == 0) {
    out_kl[0] =
        0.5f * (klred[0] + klred[1] + klred[2] + klred[3] - 406528.0f);
  }
}

extern "C" void kernel_launch(void* const* d_in, const int* in_sizes, int n_in,
                              void* d_out, int out_size, void* d_ws,
                              size_t ws_size, hipStream_t stream) {
  const float* x = (const float*)d_in[0];
  const float* w_mu1 = (const float*)d_in[1];
  const float* w_sigma1 = (const float*)d_in[2];
  const float* b_mu1 = (const float*)d_in[3];
  const float* b_sigma1 = (const float*)d_in[4];
  const float* w_mu2 = (const float*)d_in[5];
  const float* w_sigma2 = (const float*)d_in[6];
  const float* b_mu2 = (const float*)d_in[7];
  const float* b_sigma2 = (const float*)d_in[8];

  float* out = (float*)d_out;
  float* out_p = out;             // 256*10
  float* out_sigma = out + 2560;  // 256*100
  float* out_kl = out + 28160;    // 1

  float* ws = (float*)d_ws;
  float* mu_part = ws;                            // 8*256*512
  float* q_part = ws + SPLITS * BATCH * DH;       // 8*256*512
  float* kl_part = ws + 2 * SPLITS * BATCH * DH;  // 136

  gemm1_kernel<<<dim3(8, 16, 8), 256, 0, stream>>>(
      x, w_mu1, w_sigma1, w_mu2, w_sigma2, mu_part, q_part, kl_part);
  layer2_kernel<<<256, 256, 0, stream>>>(mu_part, q_part, b_mu1, b_sigma1,
                                         w_mu2, w_sigma2, b_mu2, b_sigma2,
                                         kl_part, out_p, out_sigma, out_kl);
}

// Round 5
// 128.309 us; speedup vs baseline: 1.4682x; 1.0148x over previous
//
#include <hip/hip_runtime.h>
#include <math.h>

#define BATCH 256
#define DIN 784
#define DH 512
#define DOUT 10
#define SPLITS 16
#define KSPL 49  // 784 / 16

// Fast softplus: w_sigma* inputs are uniform[-12,-2]; native v_exp/v_log give
// ~1e-7 rel error -- output threshold is ~2% relative. Verified absmax 1.9e-6.
__device__ __forceinline__ float softplus(float x) {
  return __logf(1.0f + __expf(x));
}

// ---------------------------------------------------------------------------
// Kernel 1: layer-1 dual GEMM, k-split. Grid (8 hTiles, 16 bTiles, 16 splits)
// = 2048 blocks. Block tile: 64 h x 16 b, k-chunk 49. ALL operands staged in
// LDS (wmt = w_mu1 tile, wst = softplus(w_sigma1) transposed tile, xs = x
// rows) so the K-loop has zero global-latency stalls. Thread: 2 h x 2 b.
//   mu_part[s][b][h] = sum_k x[b,k] * w_mu1[k,h]
//   q_part [s][b][h] = sum_k x[b,k]^2 * softplus(w_sigma1[h,k])
// KL partials (no atomics, no init): 272 slots in kl_part
//   y==0: sum (sp - log sp) over wst tile (from LDS)   -> slot x*16+s
//   y==1: sum w_mu1^2 over wmt tile (from LDS)         -> slot 128+x*16+s
//   y==2,x==0: sp(ws2)-log sp(ws2) + w_mu2^2 slice     -> slot 256+s
// ---------------------------------------------------------------------------
__global__ __launch_bounds__(256) void gemm1_kernel(
    const float* __restrict__ x, const float* __restrict__ w_mu1,
    const float* __restrict__ w_sigma1, const float* __restrict__ w_mu2,
    const float* __restrict__ w_sigma2, float* __restrict__ mu_part,
    float* __restrict__ q_part, float* __restrict__ kl_part) {
  __shared__ float xs[16][KSPL];
  __shared__ float wmt[KSPL][66];  // [k][h], pad 64->66 (2-way max, free)
  __shared__ float wst[KSPL][66];
  __shared__ float rlds[4];
  const int t = threadIdx.x;
  const int h0 = blockIdx.x * 64;
  const int b0 = blockIdx.y * 16;
  const int s = blockIdx.z;
  const int i0 = s * KSPL;
  const int hl = (t & 31) * 2;  // even h offset in tile
  const int bl = t >> 5;        // 0..7

  // stage x rows (16 x 49, coalesced 49-chunks)
  for (int f = t; f < 16 * KSPL; f += 256) {
    const int bb = f / KSPL, kk = f - bb * KSPL;
    xs[bb][kk] = x[(b0 + bb) * DIN + i0 + kk];
  }
  // stage w_mu1 tile (49 x 64, coalesced 64-rows)
  for (int f = t; f < KSPL * 64; f += 256) {
    const int kk = f >> 6, hh = f & 63;
    wmt[kk][hh] = w_mu1[(i0 + kk) * DH + h0 + hh];
  }
  // stage softplus(w_sigma1) tile, transposed to [k][h]
  for (int f = t; f < 64 * KSPL; f += 256) {
    const int hh = f / KSPL, kk = f - hh * KSPL;
    wst[kk][hh] = softplus(w_sigma1[(h0 + hh) * DIN + i0 + kk]);
  }
  __syncthreads();

  float mu00 = 0.f, mu10 = 0.f, mu01 = 0.f, mu11 = 0.f;
  float q00 = 0.f, q10 = 0.f, q01 = 0.f, q11 = 0.f;

#pragma unroll 7
  for (int kk = 0; kk < KSPL; kk++) {
    const float2 wmv = *(const float2*)&wmt[kk][hl];
    const float2 wsv = *(const float2*)&wst[kk][hl];
    const float xa = xs[bl][kk];
    const float xb = xs[bl + 8][kk];
    const float xa2 = xa * xa;
    const float xb2 = xb * xb;
    mu00 = fmaf(wmv.x, xa, mu00);
    mu10 = fmaf(wmv.y, xa, mu10);
    mu01 = fmaf(wmv.x, xb, mu01);
    mu11 = fmaf(wmv.y, xb, mu11);
    q00 = fmaf(wsv.x, xa2, q00);
    q10 = fmaf(wsv.y, xa2, q10);
    q01 = fmaf(wsv.x, xb2, q01);
    q11 = fmaf(wsv.y, xb2, q11);
  }

  const int h = h0 + hl;
  const int bA = b0 + bl, bB = b0 + bl + 8;
  const size_t base = (size_t)s * (BATCH * DH);
  *(float2*)&mu_part[base + (size_t)bA * DH + h] = make_float2(mu00, mu10);
  *(float2*)&mu_part[base + (size_t)bB * DH + h] = make_float2(mu01, mu11);
  *(float2*)&q_part[base + (size_t)bA * DH + h] = make_float2(q00, q10);
  *(float2*)&q_part[base + (size_t)bB * DH + h] = make_float2(q01, q11);

  // ---- fused KL partials (tile scans hit LDS, not global) ----
  float kl = 0.f;
  int slot = -1;
  if (blockIdx.y == 0) {
    for (int f = t; f < KSPL * 64; f += 256) {
      const int kk = f >> 6, hh = f & 63;
      const float sv = wst[kk][hh];
      kl += sv - __logf(sv);
    }
    slot = blockIdx.x * 16 + s;
  } else if (blockIdx.y == 1) {
    for (int f = t; f < KSPL * 64; f += 256) {
      const int kk = f >> 6, hh = f & 63;
      const float wv = wmt[kk][hh];
      kl = fmaf(wv, wv, kl);
    }
    slot = 128 + blockIdx.x * 16 + s;
  } else if (blockIdx.y == 2 && blockIdx.x == 0) {
    for (int idx = s * 320 + t; idx < s * 320 + 320; idx += 256) {
      const float sv = softplus(w_sigma2[idx]);
      const float wv = w_mu2[idx];
      kl += sv - __logf(sv);
      kl = fmaf(wv, wv, kl);
    }
    slot = 256 + s;
  }

  for (int off = 32; off > 0; off >>= 1) kl += __shfl_down(kl, off);
  const int lane = t & 63, wv = t >> 6;
  if (lane == 0) rlds[wv] = kl;
  __syncthreads();
  if (t == 0 && slot >= 0)
    kl_part[slot] = rlds[0] + rlds[1] + rlds[2] + rlds[3];
}

// ---------------------------------------------------------------------------
// Kernel 2: fused layer-1 epilogue + layer-2 + softmax + Jacobian sandwich +
// KL finalize. One block (256 threads) per batch row.
// ---------------------------------------------------------------------------
__global__ __launch_bounds__(256) void layer2_kernel(
    const float* __restrict__ mu_part, const float* __restrict__ q_part,
    const float* __restrict__ b_mu1, const float* __restrict__ b_sigma1,
    const float* __restrict__ w_mu2, const float* __restrict__ w_sigma2,
    const float* __restrict__ b_mu2, const float* __restrict__ b_sigma2,
    const float* __restrict__ kl_part, float* __restrict__ out_p,
    float* __restrict__ out_sigma, float* __restrict__ out_kl) {
  const int b = blockIdx.x, t = threadIdx.x;
  __shared__ float red[4][75];
  __shared__ float fin[75];
  __shared__ float mu3[10], pvec[10], trv[10], spb2[10];
  __shared__ float sig[10][10], Tm[10][10], cs[10], rs[10];
  __shared__ float klred[4];

  // reduce k-split partials for this batch's two h values per thread
  float musum0 = 0.f, musum1 = 0.f, qsum0 = 0.f, qsum1 = 0.f;
#pragma unroll
  for (int s2 = 0; s2 < SPLITS; s2++) {
    const size_t base = (size_t)s2 * (BATCH * DH) + (size_t)b * DH;
    musum0 += mu_part[base + t];
    musum1 += mu_part[base + t + 256];
    qsum0 += q_part[base + t];
    qsum1 += q_part[base + t + 256];
  }

  float m2v[2], d2v[2];
  {
    const float ma0 = musum0 + b_mu1[t];
    const float ma1 = musum1 + b_mu1[t + 256];
    m2v[0] = ma0 > 0.f ? ma0 : 0.f;
    m2v[1] = ma1 > 0.f ? ma1 : 0.f;
    d2v[0] = ma0 > 0.f ? (qsum0 + softplus(b_sigma1[t])) : 0.f;
    d2v[1] = ma1 > 0.f ? (qsum1 + softplus(b_sigma1[t + 256])) : 0.f;
  }

  float acc[75];
#pragma unroll
  for (int i = 0; i < 75; i++) acc[i] = 0.f;

#pragma unroll
  for (int hh = 0; hh < 2; hh++) {
    const int h = t + hh * 256;
    const float m2h = m2v[hh], d2h = d2v[hh];
    const float msq = m2h * m2h;
    float wrow[10];
#pragma unroll
    for (int o = 0; o < 10; o++) wrow[o] = w_mu2[h * 10 + o];
#pragma unroll
    for (int o = 0; o < 10; o++) {
      acc[o] = fmaf(wrow[o], m2h, acc[o]);
      acc[10 + o] = fmaf(softplus(w_sigma2[o * DH + h]), msq, acc[10 + o]);
    }
    int idx = 20;
#pragma unroll
    for (int o = 0; o < 10; o++) {
      const float wd = wrow[o] * d2h;
#pragma unroll
      for (int p = o; p < 10; p++) {
        acc[idx] = fmaf(wd, wrow[p], acc[idx]);
        idx++;
      }
    }
  }

  const int lane = t & 63, wv = t >> 6;
#pragma unroll
  for (int j = 0; j < 75; j++) {
    float v = acc[j];
    for (int off = 32; off > 0; off >>= 1) v += __shfl_down(v, off);
    if (lane == 0) red[wv][j] = v;
  }
  __syncthreads();
  if (t < 75) fin[t] = red[0][t] + red[1][t] + red[2][t] + red[3][t];
  __syncthreads();

  if (t < 10) {
    mu3[t] = fin[t] + b_mu2[t];
    spb2[t] = softplus(b_sigma2[t]);
    // faithful replication of the reshape-trace: tr[b,o] = tr_raw[o2, c];
    // needs d2[cc][cc], d2[cc][256+cc] of OTHER batches -> recompute.
    const int c0 = b * 10 + t;
    const int o2 = c0 >> 8, cc = c0 & 255;
    float mua = b_mu1[cc], qa = 0.f;
    float mub = b_mu1[256 + cc], qb = 0.f;
#pragma unroll
    for (int s2 = 0; s2 < SPLITS; s2++) {
      const size_t base = (size_t)s2 * (BATCH * DH) + (size_t)cc * DH;
      mua += mu_part[base + cc];
      qa += q_part[base + cc];
      mub += mu_part[base + 256 + cc];
      qb += q_part[base + 256 + cc];
    }
    const float d2aa = mua > 0.f ? (qa + softplus(b_sigma1[cc])) : 0.f;
    const float d2bb = mub > 0.f ? (qb + softplus(b_sigma1[256 + cc])) : 0.f;
    trv[t] = softplus(w_sigma2[o2 * DH + 2 * cc]) * d2aa +
             softplus(w_sigma2[o2 * DH + 2 * cc + 1]) * d2bb;
  }
  __syncthreads();

  if (t == 0) {
    float mx = mu3[0];
#pragma unroll
    for (int o = 1; o < 10; o++) mx = fmaxf(mx, mu3[o]);
    float e[10], se = 0.f;
#pragma unroll
    for (int o = 0; o < 10; o++) {
      e[o] = expf(mu3[o] - mx);
      se += e[o];
    }
    const float inv = 1.f / se;
#pragma unroll
    for (int o = 0; o < 10; o++) pvec[o] = e[o] * inv;
  }
  __syncthreads();

  if (t < 100) {
    const int o = t / 10, p = t % 10;
    const int i0 = o < p ? o : p, j0 = o < p ? p : o;
    const int idx = 10 * i0 - (i0 * (i0 - 1)) / 2 + (j0 - i0);
    float v = fin[20 + idx];  // mid[o][p]
    if (o == p) v += trv[o] + fin[10 + o] + spb2[o];
    sig[o][p] = v;
  }
  __syncthreads();

  if (t < 10) {  // cs[k] = sum_j p[j] * sig[j][k]
    float s = 0.f;
#pragma unroll
    for (int j = 0; j < 10; j++) s = fmaf(pvec[j], sig[j][t], s);
    cs[t] = s;
  }
  __syncthreads();

  if (t < 100) {  // T[i][k] = p[i] * (sig[i][k] - cs[k])
    const int o = t / 10, p = t % 10;
    Tm[o][p] = pvec[o] * (sig[o][p] - cs[p]);
  }
  __syncthreads();

  if (t < 10) {  // rs[i] = sum_k T[i][k] * p[k]
    float s = 0.f;
#pragma unroll
    for (int k = 0; k < 10; k++) s = fmaf(Tm[t][k], pvec[k], s);
    rs[t] = s;
  }
  __syncthreads();

  if (t < 100) {  // Sigma_out[i][l] = p[l] * (T[i][l] - rs[i])
    const int o = t / 10, p = t % 10;
    out_sigma[b * 100 + t] = pvec[p] * (Tm[o][p] - rs[o]);
  }
  if (t < 10) out_p[b * 10 + t] = pvec[t];

  // ---- KL finalize (block 0 only; sync executed uniformly by all) ----
  float klv = 0.f;
  if (b == 0) {
    klv = kl_part[t];
    if (t < 16) klv += kl_part[256 + t];
  }
  for (int off = 32; off > 0; off >>= 1) klv += __shfl_down(klv, off);
  if (lane == 0) klred[wv] = klv;
  __syncthreads();
  if (b == 0 && t == 0) {
    out_kl[0] =
        0.5f * (klred[0] + klred[1] + klred[2] + klred[3] - 406528.0f);
  }
}

extern "C" void kernel_launch(void* const* d_in, const int* in_sizes, int n_in,
                              void* d_out, int out_size, void* d_ws,
                              size_t ws_size, hipStream_t stream) {
  const float* x = (const float*)d_in[0];
  const float* w_mu1 = (const float*)d_in[1];
  const float* w_sigma1 = (const float*)d_in[2];
  const float* b_mu1 = (const float*)d_in[3];
  const float* b_sigma1 = (const float*)d_in[4];
  const float* w_mu2 = (const float*)d_in[5];
  const float* w_sigma2 = (const float*)d_in[6];
  const float* b_mu2 = (const float*)d_in[7];
  const float* b_sigma2 = (const float*)d_in[8];

  float* out = (float*)d_out;
  float* out_p = out;             // 256*10
  float* out_sigma = out + 2560;  // 256*100
  float* out_kl = out + 28160;    // 1

  float* ws = (float*)d_ws;
  float* mu_part = ws;                            // 16*256*512
  float* q_part = ws + SPLITS * BATCH * DH;       // 16*256*512
  float* kl_part = ws + 2 * SPLITS * BATCH * DH;  // 272

  gemm1_kernel<<<dim3(8, 16, 16), 256, 0, stream>>>(
      x, w_mu1, w_sigma1, w_mu2, w_sigma2, mu_part, q_part, kl_part);
  layer2_kernel<<<256, 256, 0, stream>>>(mu_part, q_part, b_mu1, b_sigma1,
                                         w_mu2, w_sigma2, b_mu2, b_sigma2,
                                         kl_part, out_p, out_sigma, out_kl);
}

// Round 6
// 122.313 us; speedup vs baseline: 1.5401x; 1.0490x over previous
//
#include <hip/hip_runtime.h>
#include <math.h>

#define BATCH 256
#define DIN 784
#define DH 512
#define DOUT 10
#define SPLITS 16
#define KSPL 49  // 784 / 16

// Fast softplus: w_sigma* inputs are uniform[-12,-2]; native v_exp/v_log give
// ~1e-7 rel error -- output threshold is ~2% relative. Verified absmax 1.9e-6.
__device__ __forceinline__ float softplus(float x) {
  return __logf(1.0f + __expf(x));
}

// ---------------------------------------------------------------------------
// Kernel 1: layer-1 dual GEMM, k-split. Grid (8 hTiles, 4 bTiles, 16 splits)
// = 512 blocks. Block tile: 64 h x 64 b, k-chunk 49 (padded to 50 with a
// zero column so the k-pair loop needs no tail). Thread: 4 h x 4 b, k-pair
// unroll -> per 2 k-steps: 4 ds_read_b128 + 4 ds_read_b64 feed 128 FMAs
// (vs 0.25 LDS instr/FMA before; now 0.0625 -- LDS pipe was the limiter).
//   mu_part[s][b][h] = sum_k x[b,k] * w_mu1[k,h]
//   q_part [s][b][h] = sum_k x[b,k]^2 * softplus(w_sigma1[h,k])
// KL partials (no atomics, no init): 272 slots in kl_part
//   y==0: sum (sp - log sp) over wst tile (from LDS)   -> slot x*16+s
//   y==1: sum w_mu1^2 over wmt tile (from LDS)         -> slot 128+x*16+s
//   y==2,x==0: sp(ws2)-log sp(ws2) + w_mu2^2 slice     -> slot 256+s
// ---------------------------------------------------------------------------
__global__ __launch_bounds__(256) void gemm1_kernel(
    const float* __restrict__ x, const float* __restrict__ w_mu1,
    const float* __restrict__ w_sigma1, const float* __restrict__ w_mu2,
    const float* __restrict__ w_sigma2, float* __restrict__ mu_part,
    float* __restrict__ q_part, float* __restrict__ kl_part) {
  __shared__ float xs[64][50];     // [b][k], k padded 49->50 (b64 alignment)
  __shared__ float wmt[50][68];    // [k][h], h padded 64->68 (b128 alignment)
  __shared__ float wst[50][68];
  __shared__ float rlds[4];
  const int t = threadIdx.x;
  const int h0 = blockIdx.x * 64;
  const int b0 = blockIdx.y * 64;
  const int s = blockIdx.z;
  const int i0 = s * KSPL;
  const int hl = (t & 15) * 4;   // 16 h-groups of 4
  const int bg = (t >> 4) * 4;   // 16 b-groups of 4

  // stage x rows (64 x 49)
  for (int f = t; f < 64 * KSPL; f += 256) {
    const int bb = f / KSPL, kk = f - bb * KSPL;
    xs[bb][kk] = x[(b0 + bb) * DIN + i0 + kk];
  }
  // stage w_mu1 tile (49 x 64, coalesced 64-rows)
  for (int f = t; f < KSPL * 64; f += 256) {
    const int kk = f >> 6, hh = f & 63;
    wmt[kk][hh] = w_mu1[(i0 + kk) * DH + h0 + hh];
  }
  // stage softplus(w_sigma1) tile, transposed to [k][h]
  for (int f = t; f < 64 * KSPL; f += 256) {
    const int hh = f / KSPL, kk = f - hh * KSPL;
    wst[kk][hh] = softplus(w_sigma1[(h0 + hh) * DIN + i0 + kk]);
  }
  // zero the k=49 pad column/rows (k-pair loop reads them)
  if (t < 64) {
    xs[t][49] = 0.f;
    wmt[49][t] = 0.f;
    wst[49][t] = 0.f;
  }
  __syncthreads();

  float mu[4][4], qq[4][4];
#pragma unroll
  for (int j = 0; j < 4; j++)
#pragma unroll
    for (int i = 0; i < 4; i++) {
      mu[j][i] = 0.f;
      qq[j][i] = 0.f;
    }

#pragma unroll 5
  for (int kk = 0; kk < 50; kk += 2) {
    const float4 wm0 = *(const float4*)&wmt[kk][hl];
    const float4 wm1 = *(const float4*)&wmt[kk + 1][hl];
    const float4 ws0 = *(const float4*)&wst[kk][hl];
    const float4 ws1 = *(const float4*)&wst[kk + 1][hl];
    const float* wm0a = (const float*)&wm0;
    const float* wm1a = (const float*)&wm1;
    const float* ws0a = (const float*)&ws0;
    const float* ws1a = (const float*)&ws1;
#pragma unroll
    for (int j = 0; j < 4; j++) {
      const float2 xv = *(const float2*)&xs[bg + j][kk];
      const float xx = xv.x, xy = xv.y;
      const float x2 = xx * xx, y2 = xy * xy;
#pragma unroll
      for (int i = 0; i < 4; i++) {
        mu[j][i] = fmaf(wm0a[i], xx, mu[j][i]);
        mu[j][i] = fmaf(wm1a[i], xy, mu[j][i]);
        qq[j][i] = fmaf(ws0a[i], x2, qq[j][i]);
        qq[j][i] = fmaf(ws1a[i], y2, qq[j][i]);
      }
    }
  }

  const int h = h0 + hl;
  const size_t base = (size_t)s * (BATCH * DH);
#pragma unroll
  for (int j = 0; j < 4; j++) {
    const size_t row = base + (size_t)(b0 + bg + j) * DH + h;
    *(float4*)&mu_part[row] = make_float4(mu[j][0], mu[j][1], mu[j][2], mu[j][3]);
    *(float4*)&q_part[row] = make_float4(qq[j][0], qq[j][1], qq[j][2], qq[j][3]);
  }

  // ---- fused KL partials (tile scans hit LDS, not global) ----
  float kl = 0.f;
  int slot = -1;
  if (blockIdx.y == 0) {
    for (int f = t; f < KSPL * 64; f += 256) {
      const int kk = f >> 6, hh = f & 63;
      const float sv = wst[kk][hh];
      kl += sv - __logf(sv);
    }
    slot = blockIdx.x * 16 + s;
  } else if (blockIdx.y == 1) {
    for (int f = t; f < KSPL * 64; f += 256) {
      const int kk = f >> 6, hh = f & 63;
      const float wv = wmt[kk][hh];
      kl = fmaf(wv, wv, kl);
    }
    slot = 128 + blockIdx.x * 16 + s;
  } else if (blockIdx.y == 2 && blockIdx.x == 0) {
    for (int idx = s * 320 + t; idx < s * 320 + 320; idx += 256) {
      const float sv = softplus(w_sigma2[idx]);
      const float wv = w_mu2[idx];
      kl += sv - __logf(sv);
      kl = fmaf(wv, wv, kl);
    }
    slot = 256 + s;
  }

  for (int off = 32; off > 0; off >>= 1) kl += __shfl_down(kl, off);
  const int lane = t & 63, wv = t >> 6;
  if (lane == 0) rlds[wv] = kl;
  __syncthreads();
  if (t == 0 && slot >= 0)
    kl_part[slot] = rlds[0] + rlds[1] + rlds[2] + rlds[3];
}

// ---------------------------------------------------------------------------
// Kernel 2: fused layer-1 epilogue + layer-2 + softmax + Jacobian sandwich +
// KL finalize. One block (256 threads) per batch row. Partial reduction is
// vectorized: each thread sums one float4 of one array over 16 splits
// (16 loads vs 64 scalar), redistributed through LDS.
// ---------------------------------------------------------------------------
__global__ __launch_bounds__(256) void layer2_kernel(
    const float* __restrict__ mu_part, const float* __restrict__ q_part,
    const float* __restrict__ b_mu1, const float* __restrict__ b_sigma1,
    const float* __restrict__ w_mu2, const float* __restrict__ w_sigma2,
    const float* __restrict__ b_mu2, const float* __restrict__ b_sigma2,
    const float* __restrict__ kl_part, float* __restrict__ out_p,
    float* __restrict__ out_sigma, float* __restrict__ out_kl) {
  const int b = blockIdx.x, t = threadIdx.x;
  __shared__ float smu[DH], sq[DH];
  __shared__ float red[4][75];
  __shared__ float fin[75];
  __shared__ float mu3[10], pvec[10], trv[10], spb2[10];
  __shared__ float sig[10][10], Tm[10][10], cs[10], rs[10];
  __shared__ float klred[4];

  // vectorized split reduction: thread t -> array (t>>7), h-quad (t&127)*4
  {
    const int arr = t >> 7;
    const int h4 = (t & 127) * 4;
    const float* srcbase = (arr == 0 ? mu_part : q_part);
    const float4* src = (const float4*)(srcbase + (size_t)b * DH + h4);
    float4 a = make_float4(0.f, 0.f, 0.f, 0.f);
#pragma unroll
    for (int s2 = 0; s2 < SPLITS; s2++) {
      const float4 v = src[(size_t)s2 * (BATCH * DH / 4)];
      a.x += v.x;
      a.y += v.y;
      a.z += v.z;
      a.w += v.w;
    }
    float* dst = (arr == 0 ? smu : sq);
    *(float4*)&dst[h4] = a;
  }
  __syncthreads();

  float m2v[2], d2v[2];
  {
    const float ma0 = smu[t] + b_mu1[t];
    const float ma1 = smu[t + 256] + b_mu1[t + 256];
    m2v[0] = ma0 > 0.f ? ma0 : 0.f;
    m2v[1] = ma1 > 0.f ? ma1 : 0.f;
    d2v[0] = ma0 > 0.f ? (sq[t] + softplus(b_sigma1[t])) : 0.f;
    d2v[1] = ma1 > 0.f ? (sq[t + 256] + softplus(b_sigma1[t + 256])) : 0.f;
  }

  float acc[75];
#pragma unroll
  for (int i = 0; i < 75; i++) acc[i] = 0.f;

#pragma unroll
  for (int hh = 0; hh < 2; hh++) {
    const int h = t + hh * 256;
    const float m2h = m2v[hh], d2h = d2v[hh];
    const float msq = m2h * m2h;
    float wrow[10];
#pragma unroll
    for (int o = 0; o < 10; o++) wrow[o] = w_mu2[h * 10 + o];
#pragma unroll
    for (int o = 0; o < 10; o++) {
      acc[o] = fmaf(wrow[o], m2h, acc[o]);
      acc[10 + o] = fmaf(softplus(w_sigma2[o * DH + h]), msq, acc[10 + o]);
    }
    int idx = 20;
#pragma unroll
    for (int o = 0; o < 10; o++) {
      const float wd = wrow[o] * d2h;
#pragma unroll
      for (int p = o; p < 10; p++) {
        acc[idx] = fmaf(wd, wrow[p], acc[idx]);
        idx++;
      }
    }
  }

  const int lane = t & 63, wv = t >> 6;
#pragma unroll
  for (int j = 0; j < 75; j++) {
    float v = acc[j];
    for (int off = 32; off > 0; off >>= 1) v += __shfl_down(v, off);
    if (lane == 0) red[wv][j] = v;
  }
  __syncthreads();
  if (t < 75) fin[t] = red[0][t] + red[1][t] + red[2][t] + red[3][t];
  __syncthreads();

  if (t < 10) {
    mu3[t] = fin[t] + b_mu2[t];
    spb2[t] = softplus(b_sigma2[t]);
    // faithful replication of the reshape-trace: tr[b,o] = tr_raw[o2, c];
    // needs d2[cc][cc], d2[cc][256+cc] of OTHER batches -> recompute.
    const int c0 = b * 10 + t;
    const int o2 = c0 >> 8, cc = c0 & 255;
    float mua = b_mu1[cc], qa = 0.f;
    float mub = b_mu1[256 + cc], qb = 0.f;
#pragma unroll
    for (int s2 = 0; s2 < SPLITS; s2++) {
      const size_t base = (size_t)s2 * (BATCH * DH) + (size_t)cc * DH;
      mua += mu_part[base + cc];
      qa += q_part[base + cc];
      mub += mu_part[base + 256 + cc];
      qb += q_part[base + 256 + cc];
    }
    const float d2aa = mua > 0.f ? (qa + softplus(b_sigma1[cc])) : 0.f;
    const float d2bb = mub > 0.f ? (qb + softplus(b_sigma1[256 + cc])) : 0.f;
    trv[t] = softplus(w_sigma2[o2 * DH + 2 * cc]) * d2aa +
             softplus(w_sigma2[o2 * DH + 2 * cc + 1]) * d2bb;
  }
  __syncthreads();

  if (t == 0) {
    float mx = mu3[0];
#pragma unroll
    for (int o = 1; o < 10; o++) mx = fmaxf(mx, mu3[o]);
    float e[10], se = 0.f;
#pragma unroll
    for (int o = 0; o < 10; o++) {
      e[o] = expf(mu3[o] - mx);
      se += e[o];
    }
    const float inv = 1.f / se;
#pragma unroll
    for (int o = 0; o < 10; o++) pvec[o] = e[o] * inv;
  }
  __syncthreads();

  if (t < 100) {
    const int o = t / 10, p = t % 10;
    const int i0 = o < p ? o : p, j0 = o < p ? p : o;
    const int idx = 10 * i0 - (i0 * (i0 - 1)) / 2 + (j0 - i0);
    float v = fin[20 + idx];  // mid[o][p]
    if (o == p) v += trv[o] + fin[10 + o] + spb2[o];
    sig[o][p] = v;
  }
  __syncthreads();

  if (t < 10) {  // cs[k] = sum_j p[j] * sig[j][k]
    float s = 0.f;
#pragma unroll
    for (int j = 0; j < 10; j++) s = fmaf(pvec[j], sig[j][t], s);
    cs[t] = s;
  }
  __syncthreads();

  if (t < 100) {  // T[i][k] = p[i] * (sig[i][k] - cs[k])
    const int o = t / 10, p = t % 10;
    Tm[o][p] = pvec[o] * (sig[o][p] - cs[p]);
  }
  __syncthreads();

  if (t < 10) {  // rs[i] = sum_k T[i][k] * p[k]
    float s = 0.f;
#pragma unroll
    for (int k = 0; k < 10; k++) s = fmaf(Tm[t][k], pvec[k], s);
    rs[t] = s;
  }
  __syncthreads();

  if (t < 100) {  // Sigma_out[i][l] = p[l] * (T[i][l] - rs[i])
    const int o = t / 10, p = t % 10;
    out_sigma[b * 100 + t] = pvec[p] * (Tm[o][p] - rs[o]);
  }
  if (t < 10) out_p[b * 10 + t] = pvec[t];

  // ---- KL finalize (block 0 only; sync executed uniformly by all) ----
  float klv = 0.f;
  if (b == 0) {
    klv = kl_part[t];
    if (t < 16) klv += kl_part[256 + t];
  }
  for (int off = 32; off > 0; off >>= 1) klv += __shfl_down(klv, off);
  if (lane == 0) klred[wv] = klv;
  __syncthreads();
  if (b == 0 && t == 0) {
    out_kl[0] =
        0.5f * (klred[0] + klred[1] + klred[2] + klred[3] - 406528.0f);
  }
}

extern "C" void kernel_launch(void* const* d_in, const int* in_sizes, int n_in,
                              void* d_out, int out_size, void* d_ws,
                              size_t ws_size, hipStream_t stream) {
  const float* x = (const float*)d_in[0];
  const float* w_mu1 = (const float*)d_in[1];
  const float* w_sigma1 = (const float*)d_in[2];
  const float* b_mu1 = (const float*)d_in[3];
  const float* b_sigma1 = (const float*)d_in[4];
  const float* w_mu2 = (const float*)d_in[5];
  const float* w_sigma2 = (const float*)d_in[6];
  const float* b_mu2 = (const float*)d_in[7];
  const float* b_sigma2 = (const float*)d_in[8];

  float* out = (float*)d_out;
  float* out_p = out;             // 256*10
  float* out_sigma = out + 2560;  // 256*100
  float* out_kl = out + 28160;    // 1

  float* ws = (float*)d_ws;
  float* mu_part = ws;                            // 16*256*512
  float* q_part = ws + SPLITS * BATCH * DH;       // 16*256*512
  float* kl_part = ws + 2 * SPLITS * BATCH * DH;  // 272

  gemm1_kernel<<<dim3(8, 4, 16), 256, 0, stream>>>(
      x, w_mu1, w_sigma1, w_mu2, w_sigma2, mu_part, q_part, kl_part);
  layer2_kernel<<<256, 256, 0, stream>>>(mu_part, q_part, b_mu1, b_sigma1,
                                         w_mu2, w_sigma2, b_mu2, b_sigma2,
                                         kl_part, out_p, out_sigma, out_kl);
}

// Round 7
// 116.257 us; speedup vs baseline: 1.6204x; 1.0521x over previous
//
#include <hip/hip_runtime.h>
#include <math.h>

#define BATCH 256
#define DIN 784
#define DH 512
#define DOUT 10
#define SPLITS 28
#define KSPL 28  // 784 / 28, even -> no k-pad needed

// Fast softplus: w_sigma* inputs are uniform[-12,-2]; native v_exp/v_log give
// ~1e-7 rel error -- output threshold is ~2% relative. Verified absmax 1.9e-6.
__device__ __forceinline__ float softplus(float x) {
  return __logf(1.0f + __expf(x));
}

// ---------------------------------------------------------------------------
// Kernel 1: layer-1 dual GEMM, k-split. Grid (8 hTiles, 4 bTiles, 28 splits)
// = 896 blocks (~3.5/CU, 14 waves/CU; LDS 22.5 KB/block). Block tile:
// 64 h x 64 b, k-chunk 28. Thread: 4 h x 4 b, k-pair unroll -> per 2 k-steps:
// 4 ds_read_b128 + 4 ds_read_b64 feed 128 FMAs. Same aggregate LDS-pipe
// cycles as SPLITS=16 but 14 waves/CU hide staging/drain latency.
//   mu_part[s][b][h] = sum_k x[b,k] * w_mu1[k,h]
//   q_part [s][b][h] = sum_k x[b,k]^2 * softplus(w_sigma1[h,k])
// KL partials (no atomics, no init): 464 slots in kl_part
//   y==0: sum (sp - log sp) over wst tile (LDS)       -> slot x*28+s
//   y==1: sum w_mu1^2 over wmt tile (LDS)             -> slot 224+x*28+s
//   y==2,x==0,s<16: sp(ws2)-log sp(ws2)+w_mu2^2 slice -> slot 448+s
// ---------------------------------------------------------------------------
__global__ __launch_bounds__(256) void gemm1_kernel(
    const float* __restrict__ x, const float* __restrict__ w_mu1,
    const float* __restrict__ w_sigma1, const float* __restrict__ w_mu2,
    const float* __restrict__ w_sigma2, float* __restrict__ mu_part,
    float* __restrict__ q_part, float* __restrict__ kl_part) {
  __shared__ float xs[64][KSPL];    // [b][k], 112B rows (8B-aligned pairs)
  __shared__ float wmt[KSPL][68];   // [k][h], h padded 64->68 (b128 aligned)
  __shared__ float wst[KSPL][68];
  __shared__ float rlds[4];
  const int t = threadIdx.x;
  const int h0 = blockIdx.x * 64;
  const int b0 = blockIdx.y * 64;
  const int s = blockIdx.z;
  const int i0 = s * KSPL;
  const int hl = (t & 15) * 4;  // 16 h-groups of 4
  const int bg = (t >> 4) * 4;  // 16 b-groups of 4

  // stage x rows (64 x 28, coalesced 28-chunks)
  for (int f = t; f < 64 * KSPL; f += 256) {
    const int bb = f / KSPL, kk = f - bb * KSPL;
    xs[bb][kk] = x[(b0 + bb) * DIN + i0 + kk];
  }
  // stage w_mu1 tile (28 x 64, coalesced 64-rows)
  for (int f = t; f < KSPL * 64; f += 256) {
    const int kk = f >> 6, hh = f & 63;
    wmt[kk][hh] = w_mu1[(i0 + kk) * DH + h0 + hh];
  }
  // stage softplus(w_sigma1) tile, transposed to [k][h]
  for (int f = t; f < 64 * KSPL; f += 256) {
    const int hh = f / KSPL, kk = f - hh * KSPL;
    wst[kk][hh] = softplus(w_sigma1[(h0 + hh) * DIN + i0 + kk]);
  }
  __syncthreads();

  float mu[4][4], qq[4][4];
#pragma unroll
  for (int j = 0; j < 4; j++)
#pragma unroll
    for (int i = 0; i < 4; i++) {
      mu[j][i] = 0.f;
      qq[j][i] = 0.f;
    }

#pragma unroll 7
  for (int kk = 0; kk < KSPL; kk += 2) {
    const float4 wm0 = *(const float4*)&wmt[kk][hl];
    const float4 wm1 = *(const float4*)&wmt[kk + 1][hl];
    const float4 ws0 = *(const float4*)&wst[kk][hl];
    const float4 ws1 = *(const float4*)&wst[kk + 1][hl];
    const float* wm0a = (const float*)&wm0;
    const float* wm1a = (const float*)&wm1;
    const float* ws0a = (const float*)&ws0;
    const float* ws1a = (const float*)&ws1;
#pragma unroll
    for (int j = 0; j < 4; j++) {
      const float2 xv = *(const float2*)&xs[bg + j][kk];
      const float xx = xv.x, xy = xv.y;
      const float x2 = xx * xx, y2 = xy * xy;
#pragma unroll
      for (int i = 0; i < 4; i++) {
        mu[j][i] = fmaf(wm0a[i], xx, mu[j][i]);
        mu[j][i] = fmaf(wm1a[i], xy, mu[j][i]);
        qq[j][i] = fmaf(ws0a[i], x2, qq[j][i]);
        qq[j][i] = fmaf(ws1a[i], y2, qq[j][i]);
      }
    }
  }

  const int h = h0 + hl;
  const size_t base = (size_t)s * (BATCH * DH);
#pragma unroll
  for (int j = 0; j < 4; j++) {
    const size_t row = base + (size_t)(b0 + bg + j) * DH + h;
    *(float4*)&mu_part[row] =
        make_float4(mu[j][0], mu[j][1], mu[j][2], mu[j][3]);
    *(float4*)&q_part[row] =
        make_float4(qq[j][0], qq[j][1], qq[j][2], qq[j][3]);
  }

  // ---- fused KL partials (tile scans hit LDS, not global) ----
  float kl = 0.f;
  int slot = -1;
  if (blockIdx.y == 0) {
    for (int f = t; f < KSPL * 64; f += 256) {
      const int kk = f >> 6, hh = f & 63;
      const float sv = wst[kk][hh];
      kl += sv - __logf(sv);
    }
    slot = blockIdx.x * 28 + s;
  } else if (blockIdx.y == 1) {
    for (int f = t; f < KSPL * 64; f += 256) {
      const int kk = f >> 6, hh = f & 63;
      const float wv = wmt[kk][hh];
      kl = fmaf(wv, wv, kl);
    }
    slot = 224 + blockIdx.x * 28 + s;
  } else if (blockIdx.y == 2 && blockIdx.x == 0 && s < 16) {
    for (int idx = s * 320 + t; idx < s * 320 + 320; idx += 256) {
      const float sv = softplus(w_sigma2[idx]);
      const float wv = w_mu2[idx];
      kl += sv - __logf(sv);
      kl = fmaf(wv, wv, kl);
    }
    slot = 448 + s;
  }

  for (int off = 32; off > 0; off >>= 1) kl += __shfl_down(kl, off);
  const int lane = t & 63, wv = t >> 6;
  if (lane == 0) rlds[wv] = kl;
  __syncthreads();
  if (t == 0 && slot >= 0)
    kl_part[slot] = rlds[0] + rlds[1] + rlds[2] + rlds[3];
}

// ---------------------------------------------------------------------------
// Kernel 2: fused layer-1 epilogue + layer-2 + softmax + Jacobian sandwich +
// KL finalize. One block of 512 threads per batch row (8 waves/CU). Split
// reduction: thread halves each sum 14 splits of one float4; trace recompute
// parallelized over 70 threads (10 o x 7 split-groups of 4).
// ---------------------------------------------------------------------------
__global__ __launch_bounds__(512) void layer2_kernel(
    const float* __restrict__ mu_part, const float* __restrict__ q_part,
    const float* __restrict__ b_mu1, const float* __restrict__ b_sigma1,
    const float* __restrict__ w_mu2, const float* __restrict__ w_sigma2,
    const float* __restrict__ b_mu2, const float* __restrict__ b_sigma2,
    const float* __restrict__ kl_part, float* __restrict__ out_p,
    float* __restrict__ out_sigma, float* __restrict__ out_kl) {
  const int b = blockIdx.x, t = threadIdx.x;
  __shared__ float smuA[DH], sqA[DH], smuB[DH], sqB[DH];
  __shared__ float4 trp[10][7];
  __shared__ float red[8][75];
  __shared__ float fin[75];
  __shared__ float mu3[10], pvec[10], trv[10], spb2[10];
  __shared__ float sig[10][10], Tm[10][10], cs[10], rs[10];
  __shared__ float klred[8];

  // vectorized split reduction: 512 threads = 2 halves x 2 arrays x 128 quads
  {
    const int half = t >> 8;         // 0: splits 0..13, 1: splits 14..27
    const int arr = (t >> 7) & 1;    // 0: mu, 1: q
    const int h4 = (t & 127) * 4;
    const float* srcbase = (arr == 0 ? mu_part : q_part);
    const float4* src = (const float4*)(srcbase + (size_t)b * DH + h4);
    float4 a = make_float4(0.f, 0.f, 0.f, 0.f);
#pragma unroll
    for (int s2 = half * 14; s2 < half * 14 + 14; s2++) {
      const float4 v = src[(size_t)s2 * (BATCH * DH / 4)];
      a.x += v.x;
      a.y += v.y;
      a.z += v.z;
      a.w += v.w;
    }
    float* dst = (half == 0 ? (arr == 0 ? smuA : sqA)
                            : (arr == 0 ? smuB : sqB));
    *(float4*)&dst[h4] = a;
  }

  // trace recompute partials: t<70 -> (o = t/7, g = t%7) sums 4 splits
  if (t < 70) {
    const int o = t / 7, g = t % 7;
    const int cc = (b * 10 + o) & 255;
    float mua = 0.f, qa = 0.f, mub = 0.f, qb = 0.f;
#pragma unroll
    for (int s2 = 4 * g; s2 < 4 * g + 4; s2++) {
      const size_t base = (size_t)s2 * (BATCH * DH) + (size_t)cc * DH;
      mua += mu_part[base + cc];
      qa += q_part[base + cc];
      mub += mu_part[base + 256 + cc];
      qb += q_part[base + 256 + cc];
    }
    trp[o][g] = make_float4(mua, qa, mub, qb);
  }
  __syncthreads();

  const int h = t;  // one h per thread
  float m2h, d2h;
  {
    const float ma = smuA[h] + smuB[h] + b_mu1[h];
    m2h = ma > 0.f ? ma : 0.f;
    d2h = ma > 0.f ? (sqA[h] + sqB[h] + softplus(b_sigma1[h])) : 0.f;
  }

  float acc[75];
#pragma unroll
  for (int i = 0; i < 75; i++) acc[i] = 0.f;
  {
    const float msq = m2h * m2h;
    float wrow[10];
#pragma unroll
    for (int o = 0; o < 10; o++) wrow[o] = w_mu2[h * 10 + o];
#pragma unroll
    for (int o = 0; o < 10; o++) {
      acc[o] = fmaf(wrow[o], m2h, acc[o]);
      acc[10 + o] = fmaf(softplus(w_sigma2[o * DH + h]), msq, acc[10 + o]);
    }
    int idx = 20;
#pragma unroll
    for (int o = 0; o < 10; o++) {
      const float wd = wrow[o] * d2h;
#pragma unroll
      for (int p = o; p < 10; p++) {
        acc[idx] = fmaf(wd, wrow[p], acc[idx]);
        idx++;
      }
    }
  }

  const int lane = t & 63, wv = t >> 6;
#pragma unroll
  for (int j = 0; j < 75; j++) {
    float v = acc[j];
    for (int off = 32; off > 0; off >>= 1) v += __shfl_down(v, off);
    if (lane == 0) red[wv][j] = v;
  }
  __syncthreads();
  if (t < 75) {
    float v = 0.f;
#pragma unroll
    for (int w = 0; w < 8; w++) v += red[w][t];
    fin[t] = v;
  }
  __syncthreads();

  if (t < 10) {
    mu3[t] = fin[t] + b_mu2[t];
    spb2[t] = softplus(b_sigma2[t]);
    // faithful replication of the reshape-trace: tr[b,o] = tr_raw[o2, c]
    const int c0 = b * 10 + t;
    const int o2 = c0 >> 8, cc = c0 & 255;
    float mua = b_mu1[cc], qa = 0.f;
    float mub = b_mu1[256 + cc], qb = 0.f;
#pragma unroll
    for (int g = 0; g < 7; g++) {
      const float4 v = trp[t][g];
      mua += v.x;
      qa += v.y;
      mub += v.z;
      qb += v.w;
    }
    const float d2aa = mua > 0.f ? (qa + softplus(b_sigma1[cc])) : 0.f;
    const float d2bb = mub > 0.f ? (qb + softplus(b_sigma1[256 + cc])) : 0.f;
    trv[t] = softplus(w_sigma2[o2 * DH + 2 * cc]) * d2aa +
             softplus(w_sigma2[o2 * DH + 2 * cc + 1]) * d2bb;
  }
  __syncthreads();

  if (t == 0) {
    float mx = mu3[0];
#pragma unroll
    for (int o = 1; o < 10; o++) mx = fmaxf(mx, mu3[o]);
    float e[10], se = 0.f;
#pragma unroll
    for (int o = 0; o < 10; o++) {
      e[o] = __expf(mu3[o] - mx);
      se += e[o];
    }
    const float inv = 1.f / se;
#pragma unroll
    for (int o = 0; o < 10; o++) pvec[o] = e[o] * inv;
  }
  __syncthreads();

  if (t < 100) {
    const int o = t / 10, p = t % 10;
    const int i0 = o < p ? o : p, j0 = o < p ? p : o;
    const int idx = 10 * i0 - (i0 * (i0 - 1)) / 2 + (j0 - i0);
    float v = fin[20 + idx];  // mid[o][p]
    if (o == p) v += trv[o] + fin[10 + o] + spb2[o];
    sig[o][p] = v;
  }
  __syncthreads();

  if (t < 10) {  // cs[k] = sum_j p[j] * sig[j][k]
    float s = 0.f;
#pragma unroll
    for (int j = 0; j < 10; j++) s = fmaf(pvec[j], sig[j][t], s);
    cs[t] = s;
  }
  __syncthreads();

  if (t < 100) {  // T[i][k] = p[i] * (sig[i][k] - cs[k])
    const int o = t / 10, p = t % 10;
    Tm[o][p] = pvec[o] * (sig[o][p] - cs[p]);
  }
  __syncthreads();

  if (t < 10) {  // rs[i] = sum_k T[i][k] * p[k]
    float s = 0.f;
#pragma unroll
    for (int k = 0; k < 10; k++) s = fmaf(Tm[t][k], pvec[k], s);
    rs[t] = s;
  }
  __syncthreads();

  if (t < 100) {  // Sigma_out[i][l] = p[l] * (T[i][l] - rs[i])
    const int o = t / 10, p = t % 10;
    out_sigma[b * 100 + t] = pvec[p] * (Tm[o][p] - rs[o]);
  }
  if (t < 10) out_p[b * 10 + t] = pvec[t];

  // ---- KL finalize (block 0 only; sync executed uniformly by all) ----
  float klv = (b == 0 && t < 464) ? kl_part[t] : 0.f;
  for (int off = 32; off > 0; off >>= 1) klv += __shfl_down(klv, off);
  if (lane == 0) klred[wv] = klv;
  __syncthreads();
  if (b == 0 && t == 0) {
    float s = 0.f;
#pragma unroll
    for (int w = 0; w < 8; w++) s += klred[w];
    out_kl[0] = 0.5f * (s - 406528.0f);
  }
}

extern "C" void kernel_launch(void* const* d_in, const int* in_sizes, int n_in,
                              void* d_out, int out_size, void* d_ws,
                              size_t ws_size, hipStream_t stream) {
  const float* x = (const float*)d_in[0];
  const float* w_mu1 = (const float*)d_in[1];
  const float* w_sigma1 = (const float*)d_in[2];
  const float* b_mu1 = (const float*)d_in[3];
  const float* b_sigma1 = (const float*)d_in[4];
  const float* w_mu2 = (const float*)d_in[5];
  const float* w_sigma2 = (const float*)d_in[6];
  const float* b_mu2 = (const float*)d_in[7];
  const float* b_sigma2 = (const float*)d_in[8];

  float* out = (float*)d_out;
  float* out_p = out;             // 256*10
  float* out_sigma = out + 2560;  // 256*100
  float* out_kl = out + 28160;    // 1

  float* ws = (float*)d_ws;
  float* mu_part = ws;                            // 28*256*512
  float* q_part = ws + SPLITS * BATCH * DH;       // 28*256*512
  float* kl_part = ws + 2 * SPLITS * BATCH * DH;  // 464

  gemm1_kernel<<<dim3(8, 4, SPLITS), 256, 0, stream>>>(
      x, w_mu1, w_sigma1, w_mu2, w_sigma2, mu_part, q_part, kl_part);
  layer2_kernel<<<256, 512, 0, stream>>>(mu_part, q_part, b_mu1, b_sigma1,
                                         w_mu2, w_sigma2, b_mu2, b_sigma2,
                                         kl_part, out_p, out_sigma, out_kl);
}